// Round 6
// baseline (897.422 us; speedup 1.0000x reference)
//
#include <hip/hip_runtime.h>

#define DEVI __device__ __forceinline__

typedef unsigned short u16;
typedef __attribute__((ext_vector_type(8))) short s16x8;
typedef __attribute__((ext_vector_type(4))) float f32x4;
typedef __attribute__((ext_vector_type(4))) unsigned short u16x4v;
typedef __attribute__((ext_vector_type(2))) unsigned int u32x2;

constexpr int NB   = 16;
constexpr int LL   = 512;
constexpr int DD   = 512;
constexpr int FF_  = 2048;
constexpr int NROW = NB * LL;                  // 8192
constexpr float C2 = 0.17677669529663687f * 1.4426950408889634f; // scale*log2(e)
constexpr size_t QKVOFF = (size_t)NROW * DD;   // elems per Q/K/V segment

DEVI u16 f2b(float f) {
  unsigned int u = __float_as_uint(f);
  unsigned int r = u + 0x7FFFu + ((u >> 16) & 1u); // RNE
  return (u16)(r >> 16);
}

// async global->LDS, 16B per lane; LDS dest = uniform base + lane*16
DEVI void gload16(const void* g, void* l) {
  __builtin_amdgcn_global_load_lds(
      (const __attribute__((address_space(1))) unsigned int*)(unsigned long long)g,
      (__attribute__((address_space(3))) unsigned int*)(unsigned int)(unsigned long long)l,
      16, 0, 0);
}

// ---------------- elementwise helpers ----------------
__global__ __launch_bounds__(256) void k_f32_to_bf16(const float* __restrict__ X, u16* __restrict__ Y, int n4) {
  for (int i = blockIdx.x * 256 + threadIdx.x; i < n4; i += gridDim.x * 256) {
    float4 x = ((const float4*)X)[i];
    u16x4v o; o[0] = f2b(x.x); o[1] = f2b(x.y); o[2] = f2b(x.z); o[3] = f2b(x.w);
    ((u16x4v*)Y)[i] = o;
  }
}

__global__ __launch_bounds__(256) void k_zero(float* __restrict__ p, int n) {
  int i = blockIdx.x * 256 + threadIdx.x;
  if (i < n) p[i] = 0.f;
}

__global__ __launch_bounds__(256) void k_recip(float* __restrict__ p, int n) {
  int i = blockIdx.x * 256 + threadIdx.x;
  if (i < n) p[i] = 1.0f / p[i];
}

__global__ void k_catbias(const float* __restrict__ a, const float* __restrict__ b,
                          const float* __restrict__ c, float* __restrict__ o) {
  int i = blockIdx.x * 256 + threadIdx.x; // 1536
  o[i] = (i < 512) ? a[i] : (i < 1024) ? b[i - 512] : c[i - 1024];
}

// ---------------- weight transpose + convert: WT[m*K+k] = bf16(W[k*M+m]) ----------------
__global__ __launch_bounds__(256) void k_wtrans(const float* __restrict__ W, u16* __restrict__ WT, int K, int M) {
  __shared__ float tile[32][33];
  const int k0 = blockIdx.x * 32, m0 = blockIdx.y * 32;
  const int tx = threadIdx.x & 31, ty = threadIdx.x >> 5;
#pragma unroll
  for (int j = 0; j < 4; ++j) tile[ty + j * 8][tx] = W[(size_t)(k0 + ty + j * 8) * M + m0 + tx];
  __syncthreads();
#pragma unroll
  for (int j = 0; j < 4; ++j) WT[(size_t)(m0 + ty + j * 8) * K + k0 + tx] = f2b(tile[tx][ty + j * 8]);
}

// ---------------- GEMM (m97 structure): C[row,col] = act(A[row,:].Bt[col,:] + bias) ----------------
// BM x 128 tile, BK=64, 4 waves, global_load_lds staging (linear LDS).
template <int BM, int RELU, int HASB, int HASRES, int OUTF, int OUTB, int SPLIT3>
__global__ __launch_bounds__(256) void k_gemm(const u16* __restrict__ A, const u16* __restrict__ Bt,
                                              const float* __restrict__ bias, const float* __restrict__ Res,
                                              float* __restrict__ Cf, u16* __restrict__ Cb,
                                              int K, int Ncols) {
  constexpr int WR = BM / 64;        // 2 (BM=128) or 1 (BM=64)
  constexpr int WC = 4 / WR;         // 2 or 4
  constexpr int MW = 4;              // row frags per wave
  constexpr int NW = 128 / (16 * WC);// 4 or 2
  __shared__ __align__(16) u16 As[BM * 64];
  __shared__ __align__(16) u16 Bs[128 * 64];
  const int t = threadIdx.x, lane = t & 63, w = t >> 6;
  const int wr = w / WC, wc = w % WC, l16 = lane & 15, lhi = lane >> 4;
  const int row0 = blockIdx.x * BM, col0 = blockIdx.y * 128;
  const int sr = lane >> 3, sc = (lane & 7) * 8; // staging row-in-chunk / col
  const u16* Ag = A + (size_t)(row0 + sr) * K + sc;
  const u16* Bg = Bt + (size_t)(col0 + sr) * K + sc;

  f32x4 acc[MW][NW] = {};

  for (int k0 = 0; k0 < K; k0 += 64) {
    __syncthreads(); // prior LDS reads done before overwrite
#pragma unroll
    for (int j = 0; j < BM / 32; ++j) {
      const int ch = w * (BM / 32) + j;
      gload16(Ag + (size_t)(ch * 8) * K + k0, As + ch * 512);
    }
#pragma unroll
    for (int j = 0; j < 4; ++j) {
      const int ch = w * 4 + j;
      gload16(Bg + (size_t)(ch * 8) * K + k0, Bs + ch * 512);
    }
    __syncthreads(); // staging visible
#pragma unroll
    for (int kk = 0; kk < 2; ++kk) {
      s16x8 af[MW], bfv[NW];
#pragma unroll
      for (int m = 0; m < MW; ++m) af[m] = *(const s16x8*)(As + (wr * 64 + m * 16 + l16) * 64 + kk * 32 + lhi * 8);
#pragma unroll
      for (int n = 0; n < NW; ++n) bfv[n] = *(const s16x8*)(Bs + (wc * (16 * NW) + n * 16 + l16) * 64 + kk * 32 + lhi * 8);
#pragma unroll
      for (int m = 0; m < MW; ++m)
#pragma unroll
        for (int n = 0; n < NW; ++n)
          acc[m][n] = __builtin_amdgcn_mfma_f32_16x16x32_bf16(af[m], bfv[n], acc[m][n], 0, 0, 0);
    }
  }

#pragma unroll
  for (int n = 0; n < NW; ++n) {
    const int col = col0 + wc * (16 * NW) + n * 16 + l16;
    float bv = 0.f;
    if constexpr (HASB) bv = bias[col];
#pragma unroll
    for (int m = 0; m < MW; ++m) {
      const int rbase = row0 + wr * 64 + m * 16 + lhi * 4;
#pragma unroll
      for (int r = 0; r < 4; ++r) {
        float v = acc[m][n][r] + bv;
        if constexpr (RELU) v = fmaxf(v, 0.f);
        const int row = rbase + r;
        const size_t idx = (size_t)row * Ncols + col;
        if constexpr (HASRES) v += Res[idx];
        if constexpr (OUTF) Cf[idx] = v;
        if constexpr (OUTB) {
          if constexpr (SPLIT3) {
            const size_t ib = (size_t)(col >> 9) * QKVOFF + (size_t)row * DD + (col & 511);
            Cb[ib] = f2b(v);
          } else {
            Cb[idx] = f2b(v);
          }
        }
      }
    }
  }
}

// ---------------- attention pass 1: Z[q,k] = sum_n exp(scale * Q_[n,q,:].K_[n,k,:]) ----------------
// flat 1024-block grid, XCD-remapped: head (nc) pinned to one XCD -> K/Q slices stay L2-resident.
__global__ __launch_bounds__(256) void k_attn_z(const u16* __restrict__ Q, const u16* __restrict__ Kt,
                                                float* __restrict__ Z) {
  const int bid = blockIdx.x;              // 0..1023
  const int xcd = bid & 7, idx = bid >> 3; // 128 blocks per XCD
  const int nc = xcd * 2 + (idx >> 6);     // head index (n>>4), 2 per XCD
  const int ktile = (idx >> 3) & 7;
  const int qtile = idx & 7;
  const int t = threadIdx.x, lane = t & 63, w = t >> 6;
  const int l16 = lane & 15, lhi = lane >> 4;
  const int q0 = qtile * 64 + (w >> 1) * 32;
  const int k0 = ktile * 64 + (w & 1) * 32;
  const int n0 = nc * 16;
  f32x4 zac[2][2] = {};
  for (int nn = 0; nn < 16; ++nn) {
    const int n = n0 + nn, h = n >> 4, b = n & 15;
    const size_t base = (size_t)b * LL * DD + (size_t)h * 32;
    s16x8 a[2], bb[2];
#pragma unroll
    for (int mi = 0; mi < 2; ++mi) a[mi] = *(const s16x8*)(Q + base + (size_t)(q0 + mi * 16 + l16) * DD + lhi * 8);
#pragma unroll
    for (int ni = 0; ni < 2; ++ni) bb[ni] = *(const s16x8*)(Kt + base + (size_t)(k0 + ni * 16 + l16) * DD + lhi * 8);
#pragma unroll
    for (int mi = 0; mi < 2; ++mi)
#pragma unroll
      for (int ni = 0; ni < 2; ++ni) {
        f32x4 z4 = {0.f, 0.f, 0.f, 0.f};
        f32x4 s = __builtin_amdgcn_mfma_f32_16x16x32_bf16(a[mi], bb[ni], z4, 0, 0, 0);
#pragma unroll
        for (int r = 0; r < 4; ++r) zac[mi][ni][r] += exp2f(s[r] * C2);
      }
  }
#pragma unroll
  for (int mi = 0; mi < 2; ++mi)
#pragma unroll
    for (int ni = 0; ni < 2; ++ni)
#pragma unroll
      for (int r = 0; r < 4; ++r) {
        const int q = q0 + mi * 16 + lhi * 4 + r;
        const int k = k0 + ni * 16 + l16;
        atomicAdd(&Z[q * LL + k], zac[mi][ni][r]);
      }
}

// ---------------- attention pass 2: swapped-QK, XCD-remapped, 2-deep prefetch ----------------
// flat 2048-block grid: xcd=bid&7, n=xcd*32+(idx>>3), qt=idx&7 -> the 8 qt-blocks of one head
// run back-to-back on one XCD, so its 64KB K+V stays in that XCD's L2.
__global__ __launch_bounds__(256) void k_attn_pv(const u16* __restrict__ Q, const u16* __restrict__ Kt,
                                                 const u16* __restrict__ VT, const float* __restrict__ IZ,
                                                 const float* __restrict__ Res, float* __restrict__ T) {
  const int bid = blockIdx.x;              // 0..2047
  const int xcd = bid & 7, idx = bid >> 3; // 256 per XCD
  const int n  = xcd * 32 + (idx >> 3);
  const int qt = idx & 7;
  const int t = threadIdx.x, lane = t & 63, w = t >> 6;
  const int l16 = lane & 15, lhi = lane >> 4;
  const int h = n >> 4, b = n & 15;
  const int q0 = qt * 64 + w * 16;
  __shared__ __align__(16) u16 Pl[4][16 * 64]; // per-wave private -> in-wave LDS ordering suffices
  char* P = (char*)&Pl[w][0];
  const size_t base = (size_t)b * LL * DD + (size_t)h * 32;
  const u16* Kbase = Kt + base + (size_t)l16 * DD + lhi * 8; // + k*DD
  const s16x8 aq = *(const s16x8*)(Q + base + (size_t)(q0 + l16) * DD + lhi * 8);
  const float* izrow = IZ + (size_t)(q0 + l16) * LL + lhi * 4; // lane's q-row (+k per step)
  const int wxor = (l16 & 7) << 4;
  const int wbase = (l16 * 128 + lhi * 8);
  const u16* Vbase = VT + (size_t)(n * 32 + l16) * LL + lhi * 8; // + dt*16*LL + k

  f32x4 oa[2] = {};
  s16x8 bk[2][4]; float4 iz[2][4];
#pragma unroll
  for (int pf = 0; pf < 2; ++pf)
#pragma unroll
    for (int ks = 0; ks < 4; ++ks) {
      bk[pf][ks] = *(const s16x8*)(Kbase + (size_t)(pf * 64 + ks * 16) * DD);
      iz[pf][ks] = *(const float4*)(izrow + pf * 64 + ks * 16);
    }
#pragma unroll
  for (int kt = 0; kt < 8; ++kt) {
    const int cur = kt & 1;
    const int kb = kt * 64;
    // issue V loads for this kt early; consumed at the bottom (~400cy later)
    s16x8 vv[2][2];
#pragma unroll
    for (int kc = 0; kc < 2; ++kc)
#pragma unroll
      for (int dt = 0; dt < 2; ++dt)
        vv[kc][dt] = *(const s16x8*)(Vbase + (size_t)(dt * 16) * LL + kb + kc * 32);
    // QK^T on prefetched operands
    f32x4 s[4];
#pragma unroll
    for (int ks = 0; ks < 4; ++ks) {
      f32x4 z4 = {0.f, 0.f, 0.f, 0.f};
      s[ks] = __builtin_amdgcn_mfma_f32_16x16x32_bf16(bk[cur][ks], aq, z4, 0, 0, 0);
    }
    // exp + normalize + pack + LDS write
#pragma unroll
    for (int ks = 0; ks < 4; ++ks) {
      const float p0 = exp2f(s[ks][0] * C2) * iz[cur][ks].x;
      const float p1 = exp2f(s[ks][1] * C2) * iz[cur][ks].y;
      const float p2 = exp2f(s[ks][2] * C2) * iz[cur][ks].z;
      const float p3 = exp2f(s[ks][3] * C2) * iz[cur][ks].w;
      unsigned int pk0, pk1;
      asm("v_cvt_pk_bf16_f32 %0, %1, %2" : "=v"(pk0) : "v"(p0), "v"(p1));
      asm("v_cvt_pk_bf16_f32 %0, %1, %2" : "=v"(pk1) : "v"(p2), "v"(p3));
      u32x2 pw; pw[0] = pk0; pw[1] = pk1;
      *(u32x2*)(P + ((wbase + ks * 32) ^ wxor)) = pw;
    }
    // 2-deep prefetch of K and IZ into the just-consumed slot
    if (kt < 6) {
      const int kn = kb + 128;
#pragma unroll
      for (int ks = 0; ks < 4; ++ks) {
        bk[cur][ks] = *(const s16x8*)(Kbase + (size_t)(kn + ks * 16) * DD);
        iz[cur][ks] = *(const float4*)(izrow + kn + ks * 16);
      }
    }
    // PV
#pragma unroll
    for (int kc = 0; kc < 2; ++kc) {
      const int off = (l16 * 128 + kc * 64 + lhi * 16) ^ wxor;
      const s16x8 pa = *(const s16x8*)(P + off);
#pragma unroll
      for (int dt = 0; dt < 2; ++dt)
        oa[dt] = __builtin_amdgcn_mfma_f32_16x16x32_bf16(pa, vv[kc][dt], oa[dt], 0, 0, 0);
    }
  }
#pragma unroll
  for (int dt = 0; dt < 2; ++dt)
#pragma unroll
    for (int r = 0; r < 4; ++r) {
      const size_t idx2 = (size_t)(b * LL + q0 + lhi * 4 + r) * DD + h * 32 + dt * 16 + l16;
      T[idx2] = oa[dt][r] + Res[idx2];
    }
}

// ---------------- per-head V transpose ----------------
__global__ __launch_bounds__(256) void k_vtrans(const u16* __restrict__ V, u16* __restrict__ VT) {
  const int n = blockIdx.x, lt = blockIdx.y;
  const int h = n >> 4, b = n & 15;
  const int l0 = lt * 64;
  __shared__ u16 tile[32][72];
  const int t = threadIdx.x;
  {
    const int r = t >> 2, c = (t & 3) * 8;
    s16x8 v = *(const s16x8*)(V + (size_t)(b * LL + l0 + r) * DD + h * 32 + c);
#pragma unroll
    for (int j = 0; j < 8; ++j) tile[c + j][r] = (u16)v[j];
  }
  __syncthreads();
  {
    const int d = t >> 3, ch = (t & 7) * 8;
    s16x8 o;
#pragma unroll
    for (int j = 0; j < 8; ++j) o[j] = (short)tile[d][ch + j];
    *(s16x8*)(VT + (size_t)(n * 32 + d) * LL + l0 + ch) = o;
  }
}

// ---------------- BatchNorm stats (separate pass; 256 blocks -> low atomic contention) ----------------
__global__ __launch_bounds__(256) void k_bn_stats(const float* __restrict__ X, float* __restrict__ S) {
  const int t = threadIdx.x;
  const int r0 = blockIdx.x * 32;
  float s0 = 0.f, q0 = 0.f, s1 = 0.f, q1 = 0.f;
  for (int r = 0; r < 32; ++r) {
    const float x0 = X[(size_t)(r0 + r) * DD + t];
    const float x1 = X[(size_t)(r0 + r) * DD + t + 256];
    s0 += x0; q0 += x0 * x0; s1 += x1; q1 += x1 * x1;
  }
  atomicAdd(&S[t], s0);
  atomicAdd(&S[t + 256], s1);
  atomicAdd(&S[512 + t], q0);
  atomicAdd(&S[512 + t + 256], q1);
}

// finalize (reads sums, writes coef, re-zeros sums for next accumulation)
__global__ void k_bn_fin(float* __restrict__ S, const float* __restrict__ g,
                         const float* __restrict__ be, float* __restrict__ coef) {
  const int d = threadIdx.x;
  const float inv = 1.0f / 8192.0f;
  const float mean = S[d] * inv;
  const float var = S[512 + d] * inv - mean * mean;
  const float a = rsqrtf(var + 1e-5f) * g[d];
  coef[d] = a;
  coef[512 + d] = be[d] - mean * a;
  S[d] = 0.f; S[512 + d] = 0.f;
}

template <int WB>
__global__ __launch_bounds__(256) void k_bn_apply(const float* __restrict__ X, const float* __restrict__ coef,
                                                  float* __restrict__ Yf, u16* __restrict__ Yb) {
  const int n4 = NROW * DD / 4;
  for (int i = blockIdx.x * 256 + threadIdx.x; i < n4; i += gridDim.x * 256) {
    const float4 xv = ((const float4*)X)[i];
    const int d = (i & 127) * 4;
    const float y0 = fmaf(xv.x, coef[d + 0], coef[512 + d + 0]);
    const float y1 = fmaf(xv.y, coef[d + 1], coef[512 + d + 1]);
    const float y2 = fmaf(xv.z, coef[d + 2], coef[512 + d + 2]);
    const float y3 = fmaf(xv.w, coef[d + 3], coef[512 + d + 3]);
    ((float4*)Yf)[i] = make_float4(y0, y1, y2, y3);
    if constexpr (WB) {
      u16x4v o; o[0] = f2b(y0); o[1] = f2b(y1); o[2] = f2b(y2); o[3] = f2b(y3);
      ((u16x4v*)Yb)[i] = o;
    }
  }
}

// ---------------- host launch ----------------
extern "C" void kernel_launch(void* const* d_in, const int* in_sizes, int n_in,
                              void* d_out, int out_size, void* d_ws, size_t ws_size,
                              hipStream_t stream) {
  const float* x    = (const float*)d_in[0];
  const float* emb  = (const float*)d_in[1];
  const float* bn2g = (const float*)d_in[2];
  const float* bn2b = (const float*)d_in[3];
  const float* Wq   = (const float*)d_in[4];
  const float* bq   = (const float*)d_in[5];
  const float* Wk   = (const float*)d_in[6];
  const float* bkp  = (const float*)d_in[7];
  const float* Wv   = (const float*)d_in[8];
  const float* bvp  = (const float*)d_in[9];
  const float* bnag = (const float*)d_in[10];
  const float* bnab = (const float*)d_in[11];
  const float* W1   = (const float*)d_in[12];
  const float* b1   = (const float*)d_in[13];
  const float* W2   = (const float*)d_in[14];
  const float* b2   = (const float*)d_in[15];
  const float* bnfg = (const float*)d_in[16];
  const float* bnfb = (const float*)d_in[17];

  char* p = (char*)d_ws;
  auto alloc = [&](size_t bytes) { char* r = p; p += (bytes + 255) & ~(size_t)255; return r; };
  u16*   xb    = (u16*)alloc((size_t)NROW * DD * 2);
  float* encF  = (float*)alloc((size_t)NROW * DD * 4);
  u16*   encB  = (u16*)alloc((size_t)NROW * DD * 2);
  float* tF    = (float*)alloc((size_t)NROW * DD * 4);
  u16*   qkv   = (u16*)alloc((size_t)3 * NROW * DD * 2); // Q | K | V
  u16*   VT    = (u16*)alloc((size_t)NROW * DD * 2);
  u16*   h1    = (u16*)alloc((size_t)NROW * FF_ * 2);
  float* Z     = (float*)alloc((size_t)LL * LL * 4);
  float* sums  = (float*)alloc(1024 * 4);
  float* coef  = (float*)alloc(1024 * 4);
  float* bqkv  = (float*)alloc(1536 * 4);
  u16*   embT  = (u16*)alloc((size_t)DD * DD * 2);
  u16*   wqkvT = (u16*)alloc((size_t)3 * DD * DD * 2);
  u16*   w1T   = (u16*)alloc((size_t)DD * FF_ * 2);
  u16*   w2T   = (u16*)alloc((size_t)FF_ * DD * 2);
  if ((size_t)(p - (char*)d_ws) > ws_size) return;

  auto run_bn = [&](const float* Xs, const float* g, const float* be, float* Yf, u16* Yb) {
    k_bn_stats<<<256, 256, 0, stream>>>(Xs, sums);
    k_bn_fin<<<1, 512, 0, stream>>>(sums, g, be, coef);
    if (Yb) k_bn_apply<1><<<2048, 256, 0, stream>>>(Xs, coef, Yf, Yb);
    else    k_bn_apply<0><<<2048, 256, 0, stream>>>(Xs, coef, Yf, nullptr);
  };

  k_zero<<<4, 256, 0, stream>>>(sums, 1024);
  k_f32_to_bf16<<<2048, 256, 0, stream>>>(x, xb, NROW * DD / 4);
  k_wtrans<<<dim3(16, 16), 256, 0, stream>>>(emb, embT, DD, DD);
  k_gemm<64, 0, 0, 0, 1, 0, 0><<<dim3(128, 4), 256, 0, stream>>>(xb, embT, nullptr, nullptr, tF, nullptr, DD, DD);
  run_bn(tF, bn2g, bn2b, encF, encB);

  for (int i = 0; i < 3; ++i) {
    k_wtrans<<<dim3(16, 16), 256, 0, stream>>>(Wq + (size_t)i * DD * DD, wqkvT, DD, DD);
    k_wtrans<<<dim3(16, 16), 256, 0, stream>>>(Wk + (size_t)i * DD * DD, wqkvT + (size_t)512 * DD, DD, DD);
    k_wtrans<<<dim3(16, 16), 256, 0, stream>>>(Wv + (size_t)i * DD * DD, wqkvT + (size_t)1024 * DD, DD, DD);
    k_catbias<<<6, 256, 0, stream>>>(bq + i * DD, bkp + i * DD, bvp + i * DD, bqkv);
    // fused QKV GEMM: N=1536, split-3 bf16 output
    k_gemm<128, 1, 1, 0, 0, 1, 1><<<dim3(64, 12), 256, 0, stream>>>(encB, wqkvT, bqkv, nullptr, nullptr, qkv, DD, 1536);
    k_vtrans<<<dim3(256, 8), 256, 0, stream>>>(qkv + 2 * QKVOFF, VT);
    k_zero<<<1024, 256, 0, stream>>>(Z, LL * LL);
    k_attn_z<<<1024, 256, 0, stream>>>(qkv, qkv + QKVOFF, Z);
    k_recip<<<1024, 256, 0, stream>>>(Z, LL * LL);
    k_attn_pv<<<2048, 256, 0, stream>>>(qkv, qkv + QKVOFF, VT, Z, encF, tF);
    run_bn(tF, bnag + i * DD, bnab + i * DD, encF, encB);
    k_wtrans<<<dim3(16, 64), 256, 0, stream>>>(W1 + (size_t)i * DD * FF_, w1T, DD, FF_);
    k_gemm<128, 1, 1, 0, 0, 1, 0><<<dim3(64, 16), 256, 0, stream>>>(encB, w1T, b1 + i * FF_, nullptr, nullptr, h1, DD, FF_);
    k_wtrans<<<dim3(64, 16), 256, 0, stream>>>(W2 + (size_t)i * FF_ * DD, w2T, FF_, DD);
    k_gemm<64, 0, 1, 1, 1, 0, 0><<<dim3(128, 4), 256, 0, stream>>>(h1, w2T, b2 + i * DD, encF, tF, nullptr, FF_, DD);
    float* yf = (i == 2) ? (float*)d_out : encF;
    run_bn(tF, bnfg + i * DD, bnfb + i * DD, yf, (i == 2) ? nullptr : encB);
  }
}

// Round 7
// 897.176 us; speedup vs baseline: 1.0003x; 1.0003x over previous
//
#include <hip/hip_runtime.h>

#define DEVI __device__ __forceinline__

typedef unsigned short u16;
typedef __attribute__((ext_vector_type(8))) short s16x8;
typedef __attribute__((ext_vector_type(4))) float f32x4;
typedef __attribute__((ext_vector_type(4))) unsigned short u16x4v;
typedef __attribute__((ext_vector_type(2))) unsigned int u32x2;

constexpr int NB   = 16;
constexpr int LL   = 512;
constexpr int DD   = 512;
constexpr int FF_  = 2048;
constexpr int NROW = NB * LL;                  // 8192
constexpr float C2 = 0.17677669529663687f * 1.4426950408889634f; // scale*log2(e)
constexpr size_t QKVOFF = (size_t)NROW * DD;   // elems per Q/K/V segment

DEVI u16 f2b(float f) {
  unsigned int u = __float_as_uint(f);
  unsigned int r = u + 0x7FFFu + ((u >> 16) & 1u); // RNE
  return (u16)(r >> 16);
}

DEVI float b2f(u16 v) { return __uint_as_float(((unsigned int)v) << 16); }

// async global->LDS, 16B per lane; LDS dest = uniform base + lane*16
DEVI void gload16(const void* g, void* l) {
  __builtin_amdgcn_global_load_lds(
      (const __attribute__((address_space(1))) unsigned int*)(unsigned long long)g,
      (__attribute__((address_space(3))) unsigned int*)(unsigned int)(unsigned long long)l,
      16, 0, 0);
}

// ---------------- elementwise helpers ----------------
__global__ __launch_bounds__(256) void k_f32_to_bf16(const float* __restrict__ X, u16* __restrict__ Y, int n4) {
  for (int i = blockIdx.x * 256 + threadIdx.x; i < n4; i += gridDim.x * 256) {
    float4 x = ((const float4*)X)[i];
    u16x4v o; o[0] = f2b(x.x); o[1] = f2b(x.y); o[2] = f2b(x.z); o[3] = f2b(x.w);
    ((u16x4v*)Y)[i] = o;
  }
}

__global__ __launch_bounds__(256) void k_zero(float* __restrict__ p, int n) {
  int i = blockIdx.x * 256 + threadIdx.x;
  if (i < n) p[i] = 0.f;
}

__global__ __launch_bounds__(256) void k_recip(float* __restrict__ p, int n) {
  int i = blockIdx.x * 256 + threadIdx.x;
  if (i < n) p[i] = 1.0f / p[i];
}

__global__ void k_catbias(const float* __restrict__ a, const float* __restrict__ b,
                          const float* __restrict__ c, float* __restrict__ o) {
  int i = blockIdx.x * 256 + threadIdx.x; // 1536
  o[i] = (i < 512) ? a[i] : (i < 1024) ? b[i - 512] : c[i - 1024];
}

// ---------------- weight transpose + convert: WT[m*K+k] = bf16(W[k*M+m]) ----------------
__global__ __launch_bounds__(256) void k_wtrans(const float* __restrict__ W, u16* __restrict__ WT, int K, int M) {
  __shared__ float tile[32][33];
  const int k0 = blockIdx.x * 32, m0 = blockIdx.y * 32;
  const int tx = threadIdx.x & 31, ty = threadIdx.x >> 5;
#pragma unroll
  for (int j = 0; j < 4; ++j) tile[ty + j * 8][tx] = W[(size_t)(k0 + ty + j * 8) * M + m0 + tx];
  __syncthreads();
#pragma unroll
  for (int j = 0; j < 4; ++j) WT[(size_t)(m0 + ty + j * 8) * K + k0 + tx] = f2b(tile[tx][ty + j * 8]);
}

// ---------------- GEMM (m97 structure): C[row,col] = act(A[row,:].Bt[col,:] + bias) ----------------
template <int BM, int RELU, int HASB, int HASRES, int OUTF, int OUTB, int SPLIT3>
__global__ __launch_bounds__(256) void k_gemm(const u16* __restrict__ A, const u16* __restrict__ Bt,
                                              const float* __restrict__ bias, const float* __restrict__ Res,
                                              float* __restrict__ Cf, u16* __restrict__ Cb,
                                              int K, int Ncols) {
  constexpr int WR = BM / 64;
  constexpr int WC = 4 / WR;
  constexpr int MW = 4;
  constexpr int NW = 128 / (16 * WC);
  __shared__ __align__(16) u16 As[BM * 64];
  __shared__ __align__(16) u16 Bs[128 * 64];
  const int t = threadIdx.x, lane = t & 63, w = t >> 6;
  const int wr = w / WC, wc = w % WC, l16 = lane & 15, lhi = lane >> 4;
  const int row0 = blockIdx.x * BM, col0 = blockIdx.y * 128;
  const int sr = lane >> 3, sc = (lane & 7) * 8;
  const u16* Ag = A + (size_t)(row0 + sr) * K + sc;
  const u16* Bg = Bt + (size_t)(col0 + sr) * K + sc;

  f32x4 acc[MW][NW] = {};

  for (int k0 = 0; k0 < K; k0 += 64) {
    __syncthreads();
#pragma unroll
    for (int j = 0; j < BM / 32; ++j) {
      const int ch = w * (BM / 32) + j;
      gload16(Ag + (size_t)(ch * 8) * K + k0, As + ch * 512);
    }
#pragma unroll
    for (int j = 0; j < 4; ++j) {
      const int ch = w * 4 + j;
      gload16(Bg + (size_t)(ch * 8) * K + k0, Bs + ch * 512);
    }
    __syncthreads();
#pragma unroll
    for (int kk = 0; kk < 2; ++kk) {
      s16x8 af[MW], bfv[NW];
#pragma unroll
      for (int m = 0; m < MW; ++m) af[m] = *(const s16x8*)(As + (wr * 64 + m * 16 + l16) * 64 + kk * 32 + lhi * 8);
#pragma unroll
      for (int n = 0; n < NW; ++n) bfv[n] = *(const s16x8*)(Bs + (wc * (16 * NW) + n * 16 + l16) * 64 + kk * 32 + lhi * 8);
#pragma unroll
      for (int m = 0; m < MW; ++m)
#pragma unroll
        for (int n = 0; n < NW; ++n)
          acc[m][n] = __builtin_amdgcn_mfma_f32_16x16x32_bf16(af[m], bfv[n], acc[m][n], 0, 0, 0);
    }
  }

#pragma unroll
  for (int n = 0; n < NW; ++n) {
    const int col = col0 + wc * (16 * NW) + n * 16 + l16;
    float bv = 0.f;
    if constexpr (HASB) bv = bias[col];
#pragma unroll
    for (int m = 0; m < MW; ++m) {
      const int rbase = row0 + wr * 64 + m * 16 + lhi * 4;
#pragma unroll
      for (int r = 0; r < 4; ++r) {
        float v = acc[m][n][r] + bv;
        if constexpr (RELU) v = fmaxf(v, 0.f);
        const int row = rbase + r;
        const size_t idx = (size_t)row * Ncols + col;
        if constexpr (HASRES) v += Res[idx];
        if constexpr (OUTF) Cf[idx] = v;
        if constexpr (OUTB) {
          if constexpr (SPLIT3) {
            const size_t ib = (size_t)(col >> 9) * QKVOFF + (size_t)row * DD + (col & 511);
            Cb[ib] = f2b(v);
          } else {
            Cb[idx] = f2b(v);
          }
        }
      }
    }
  }
}

// ---------------- attention pass A: E[n,q,k]=exp(scale*QK^T) (bf16), Z[q,k]+=E ----------------
// swapped mfma(K,Q): lane owns q=l16 (col), k=lhi*4+r (contiguous rows) -> 8B k-contig store.
__global__ __launch_bounds__(256) void k_attn_ze(const u16* __restrict__ Q, const u16* __restrict__ Kt,
                                                 u16* __restrict__ E, float* __restrict__ Z) {
  const int qtile = blockIdx.x, ktile = blockIdx.y, nc = blockIdx.z;
  const int t = threadIdx.x, lane = t & 63, w = t >> 6;
  const int l16 = lane & 15, lhi = lane >> 4;
  const int q0 = qtile * 64 + (w >> 1) * 32;
  const int k0 = ktile * 64 + (w & 1) * 32;
  const int n0 = nc * 16;
  f32x4 zac[2][2] = {};
  for (int nn = 0; nn < 16; ++nn) {
    const int n = n0 + nn, h = n >> 4, b = n & 15;
    const size_t base = (size_t)b * LL * DD + (size_t)h * 32;
    s16x8 a[2], bb[2];
#pragma unroll
    for (int mi = 0; mi < 2; ++mi) a[mi] = *(const s16x8*)(Q + base + (size_t)(q0 + mi * 16 + l16) * DD + lhi * 8);
#pragma unroll
    for (int ni = 0; ni < 2; ++ni) bb[ni] = *(const s16x8*)(Kt + base + (size_t)(k0 + ni * 16 + l16) * DD + lhi * 8);
#pragma unroll
    for (int mi = 0; mi < 2; ++mi)
#pragma unroll
      for (int ni = 0; ni < 2; ++ni) {
        f32x4 z4 = {0.f, 0.f, 0.f, 0.f};
        // swapped: A=K (rows=k), B=Q (cols=q) -> D[row=k-local, col=q-local]
        f32x4 s = __builtin_amdgcn_mfma_f32_16x16x32_bf16(bb[ni], a[mi], z4, 0, 0, 0);
        float e0 = exp2f(s[0] * C2), e1 = exp2f(s[1] * C2);
        float e2 = exp2f(s[2] * C2), e3 = exp2f(s[3] * C2);
        zac[mi][ni][0] += e0; zac[mi][ni][1] += e1;
        zac[mi][ni][2] += e2; zac[mi][ni][3] += e3;
        unsigned int pk0, pk1;
        asm("v_cvt_pk_bf16_f32 %0, %1, %2" : "=v"(pk0) : "v"(e0), "v"(e1));
        asm("v_cvt_pk_bf16_f32 %0, %1, %2" : "=v"(pk1) : "v"(e2), "v"(e3));
        u32x2 pw; pw[0] = pk0; pw[1] = pk1;
        const int q = q0 + mi * 16 + l16;
        const int k = k0 + ni * 16 + lhi * 4;
        *(u32x2*)(E + (size_t)n * LL * LL + (size_t)q * LL + k) = pw;
      }
  }
#pragma unroll
  for (int mi = 0; mi < 2; ++mi)
#pragma unroll
    for (int ni = 0; ni < 2; ++ni)
#pragma unroll
      for (int r = 0; r < 4; ++r) {
        const int q = q0 + mi * 16 + l16;
        const int k = k0 + ni * 16 + lhi * 4 + r;
        atomicAdd(&Z[q * LL + k], zac[mi][ni][r]);
      }
}

// ---------------- attention pass B: o[n] = (E[n]*IZ) @ V[n]^T ; T = o + Res ----------------
// Batched GEMM, 128q x 32d tile, K=512, reg-staged A with IZ scaling + XOR-swizzled LDS.
__global__ __launch_bounds__(256) void k_attn_pv2(const u16* __restrict__ E, const u16* __restrict__ VT,
                                                  const float* __restrict__ IZ, const float* __restrict__ Res,
                                                  float* __restrict__ T) {
  __shared__ __align__(16) u16 As[128 * 64];
  const int n = blockIdx.x, qt = blockIdx.y;
  const int h = n >> 4, b = n & 15;
  const int t = threadIdx.x, lane = t & 63, w = t >> 6;
  const int l16 = lane & 15, lhi = lane >> 4;
  const int sr = lane >> 3, sc = lane & 7; // staging: row-in-chunk, 8-k group
  const u16* Eg = E + (size_t)n * LL * LL + (size_t)(qt * 128 + sr) * LL + sc * 8;
  const float* IZg = IZ + (size_t)(qt * 128 + sr) * LL + sc * 8;
  const u16* Vg = VT + (size_t)(n * 32 + l16) * LL + lhi * 8;

  f32x4 acc[2][2] = {};

  for (int kt = 0; kt < 8; ++kt) {
    const int kb = kt * 64;
    // independent loads for this kt: E chunks + IZ + B fragments
    s16x8 ev[4]; float4 iza[4], izb[4];
#pragma unroll
    for (int j = 0; j < 4; ++j) {
      const int ch = w * 4 + j;
      ev[j]  = *(const s16x8*)(Eg + (size_t)(ch * 8) * LL + kb);
      iza[j] = *(const float4*)(IZg + (size_t)(ch * 8) * LL + kb);
      izb[j] = *(const float4*)(IZg + (size_t)(ch * 8) * LL + kb + 4);
    }
    s16x8 bfv[2][2];
#pragma unroll
    for (int kk = 0; kk < 2; ++kk)
#pragma unroll
      for (int nw = 0; nw < 2; ++nw)
        bfv[kk][nw] = *(const s16x8*)(Vg + (size_t)(nw * 16) * LL + kb + kk * 32);
    __syncthreads(); // prior ds_reads done before overwrite
#pragma unroll
    for (int j = 0; j < 4; ++j) {
      const int ch = w * 4 + j;
      const int row = ch * 8 + sr;
      float p0 = b2f((u16)ev[j][0]) * iza[j].x;
      float p1 = b2f((u16)ev[j][1]) * iza[j].y;
      float p2 = b2f((u16)ev[j][2]) * iza[j].z;
      float p3 = b2f((u16)ev[j][3]) * iza[j].w;
      float p4 = b2f((u16)ev[j][4]) * izb[j].x;
      float p5 = b2f((u16)ev[j][5]) * izb[j].y;
      float p6 = b2f((u16)ev[j][6]) * izb[j].z;
      float p7 = b2f((u16)ev[j][7]) * izb[j].w;
      unsigned int k0, k1, k2, k3;
      asm("v_cvt_pk_bf16_f32 %0, %1, %2" : "=v"(k0) : "v"(p0), "v"(p1));
      asm("v_cvt_pk_bf16_f32 %0, %1, %2" : "=v"(k1) : "v"(p2), "v"(p3));
      asm("v_cvt_pk_bf16_f32 %0, %1, %2" : "=v"(k2) : "v"(p4), "v"(p5));
      asm("v_cvt_pk_bf16_f32 %0, %1, %2" : "=v"(k3) : "v"(p6), "v"(p7));
      u16x4v pk; pk[0] = (u16)k0; pk[1] = (u16)(k0 >> 16); pk[2] = (u16)k1; pk[3] = (u16)(k1 >> 16);
      u16x4v pk2; pk2[0] = (u16)k2; pk2[1] = (u16)(k2 >> 16); pk2[2] = (u16)k3; pk2[3] = (u16)(k3 >> 16);
      const int byte = (row * 128 + sc * 16) ^ ((row & 7) << 4); // both-sides XOR swizzle
      *(u16x4v*)((char*)As + byte) = pk;
      *(u16x4v*)((char*)As + byte + 8) = pk2;
    }
    __syncthreads();
#pragma unroll
    for (int kk = 0; kk < 2; ++kk) {
      s16x8 af[2];
#pragma unroll
      for (int m = 0; m < 2; ++m) {
        const int row = w * 32 + m * 16 + l16;
        const int byte = (row * 128 + kk * 64 + lhi * 16) ^ ((row & 7) << 4);
        af[m] = *(const s16x8*)((const char*)As + byte);
      }
#pragma unroll
      for (int m = 0; m < 2; ++m)
#pragma unroll
        for (int nw = 0; nw < 2; ++nw)
          acc[m][nw] = __builtin_amdgcn_mfma_f32_16x16x32_bf16(af[m], bfv[kk][nw], acc[m][nw], 0, 0, 0);
    }
  }
#pragma unroll
  for (int m = 0; m < 2; ++m)
#pragma unroll
    for (int nw = 0; nw < 2; ++nw)
#pragma unroll
      for (int r = 0; r < 4; ++r) {
        const int q = qt * 128 + w * 32 + m * 16 + lhi * 4 + r;
        const size_t idx = (size_t)(b * LL + q) * DD + h * 32 + nw * 16 + l16;
        T[idx] = acc[m][nw][r] + Res[idx];
      }
}

// ---------------- fallback (old) attention kernels ----------------
__global__ __launch_bounds__(256) void k_attn_z(const u16* __restrict__ Q, const u16* __restrict__ Kt,
                                                float* __restrict__ Z) {
  const int t = threadIdx.x, lane = t & 63, w = t >> 6;
  const int l16 = lane & 15, lhi = lane >> 4;
  const int q0 = blockIdx.x * 64 + (w >> 1) * 32;
  const int k0 = blockIdx.y * 64 + (w & 1) * 32;
  const int n0 = blockIdx.z * 16;
  f32x4 zac[2][2] = {};
  for (int nn = 0; nn < 16; ++nn) {
    const int n = n0 + nn, h = n >> 4, b = n & 15;
    const size_t base = (size_t)b * LL * DD + (size_t)h * 32;
    s16x8 a[2], bb[2];
#pragma unroll
    for (int mi = 0; mi < 2; ++mi) a[mi] = *(const s16x8*)(Q + base + (size_t)(q0 + mi * 16 + l16) * DD + lhi * 8);
#pragma unroll
    for (int ni = 0; ni < 2; ++ni) bb[ni] = *(const s16x8*)(Kt + base + (size_t)(k0 + ni * 16 + l16) * DD + lhi * 8);
#pragma unroll
    for (int mi = 0; mi < 2; ++mi)
#pragma unroll
      for (int ni = 0; ni < 2; ++ni) {
        f32x4 z4 = {0.f, 0.f, 0.f, 0.f};
        f32x4 s = __builtin_amdgcn_mfma_f32_16x16x32_bf16(a[mi], bb[ni], z4, 0, 0, 0);
#pragma unroll
        for (int r = 0; r < 4; ++r) zac[mi][ni][r] += exp2f(s[r] * C2);
      }
  }
#pragma unroll
  for (int mi = 0; mi < 2; ++mi)
#pragma unroll
    for (int ni = 0; ni < 2; ++ni)
#pragma unroll
      for (int r = 0; r < 4; ++r)
        atomicAdd(&Z[(q0 + mi * 16 + lhi * 4 + r) * LL + k0 + ni * 16 + l16], zac[mi][ni][r]);
}

__global__ __launch_bounds__(256) void k_attn_pv(const u16* __restrict__ Q, const u16* __restrict__ Kt,
                                                 const u16* __restrict__ VT, const float* __restrict__ IZ,
                                                 const float* __restrict__ Res, float* __restrict__ T) {
  const int t = threadIdx.x, lane = t & 63, w = t >> 6;
  const int l16 = lane & 15, lhi = lane >> 4;
  const int n = blockIdx.x, qt = blockIdx.y;
  const int h = n >> 4, b = n & 15;
  const int q0 = qt * 64 + w * 16;
  __shared__ __align__(16) u16 Pl[4][16 * 64];
  char* P = (char*)&Pl[w][0];
  const size_t base = (size_t)b * LL * DD + (size_t)h * 32;
  const u16* Kbase = Kt + base + (size_t)l16 * DD + lhi * 8;
  const s16x8 aq = *(const s16x8*)(Q + base + (size_t)(q0 + l16) * DD + lhi * 8);
  const float* izrow = IZ + (size_t)(q0 + l16) * LL + lhi * 4;
  const int wxor = (l16 & 7) << 4;
  const int wbase = (l16 * 128 + lhi * 8);
  const u16* Vbase = VT + (size_t)(n * 32 + l16) * LL + lhi * 8;
  f32x4 oa[2] = {};
  for (int kt = 0; kt < 8; ++kt) {
    const int kb = kt * 64;
    f32x4 s[4];
#pragma unroll
    for (int ks = 0; ks < 4; ++ks) {
      const s16x8 bk = *(const s16x8*)(Kbase + (size_t)(kb + ks * 16) * DD);
      f32x4 z4 = {0.f, 0.f, 0.f, 0.f};
      s[ks] = __builtin_amdgcn_mfma_f32_16x16x32_bf16(bk, aq, z4, 0, 0, 0);
    }
#pragma unroll
    for (int ks = 0; ks < 4; ++ks) {
      const float4 iz = *(const float4*)(izrow + kb + ks * 16);
      const float p0 = exp2f(s[ks][0] * C2) * iz.x;
      const float p1 = exp2f(s[ks][1] * C2) * iz.y;
      const float p2 = exp2f(s[ks][2] * C2) * iz.z;
      const float p3 = exp2f(s[ks][3] * C2) * iz.w;
      unsigned int pk0, pk1;
      asm("v_cvt_pk_bf16_f32 %0, %1, %2" : "=v"(pk0) : "v"(p0), "v"(p1));
      asm("v_cvt_pk_bf16_f32 %0, %1, %2" : "=v"(pk1) : "v"(p2), "v"(p3));
      u32x2 pw; pw[0] = pk0; pw[1] = pk1;
      *(u32x2*)(P + ((wbase + ks * 32) ^ wxor)) = pw;
    }
#pragma unroll
    for (int kc = 0; kc < 2; ++kc) {
      const int off = (l16 * 128 + kc * 64 + lhi * 16) ^ wxor;
      const s16x8 pa = *(const s16x8*)(P + off);
#pragma unroll
      for (int dt = 0; dt < 2; ++dt) {
        const s16x8 bv = *(const s16x8*)(Vbase + (size_t)(dt * 16) * LL + kb + kc * 32);
        oa[dt] = __builtin_amdgcn_mfma_f32_16x16x32_bf16(pa, bv, oa[dt], 0, 0, 0);
      }
    }
  }
#pragma unroll
  for (int dt = 0; dt < 2; ++dt)
#pragma unroll
    for (int r = 0; r < 4; ++r) {
      const size_t idx = (size_t)(b * LL + q0 + lhi * 4 + r) * DD + h * 32 + dt * 16 + l16;
      T[idx] = oa[dt][r] + Res[idx];
    }
}

// ---------------- per-head V transpose ----------------
__global__ __launch_bounds__(256) void k_vtrans(const u16* __restrict__ V, u16* __restrict__ VT) {
  const int n = blockIdx.x, lt = blockIdx.y;
  const int h = n >> 4, b = n & 15;
  const int l0 = lt * 64;
  __shared__ u16 tile[32][72];
  const int t = threadIdx.x;
  {
    const int r = t >> 2, c = (t & 3) * 8;
    s16x8 v = *(const s16x8*)(V + (size_t)(b * LL + l0 + r) * DD + h * 32 + c);
#pragma unroll
    for (int j = 0; j < 8; ++j) tile[c + j][r] = (u16)v[j];
  }
  __syncthreads();
  {
    const int d = t >> 3, ch = (t & 7) * 8;
    s16x8 o;
#pragma unroll
    for (int j = 0; j < 8; ++j) o[j] = (short)tile[d][ch + j];
    *(s16x8*)(VT + (size_t)(n * 32 + d) * LL + l0 + ch) = o;
  }
}

// ---------------- BatchNorm ----------------
__global__ __launch_bounds__(256) void k_bn_stats(const float* __restrict__ X, float* __restrict__ S) {
  const int t = threadIdx.x;
  const int r0 = blockIdx.x * 32;
  float s0 = 0.f, q0 = 0.f, s1 = 0.f, q1 = 0.f;
  for (int r = 0; r < 32; ++r) {
    const float x0 = X[(size_t)(r0 + r) * DD + t];
    const float x1 = X[(size_t)(r0 + r) * DD + t + 256];
    s0 += x0; q0 += x0 * x0; s1 += x1; q1 += x1 * x1;
  }
  atomicAdd(&S[t], s0);
  atomicAdd(&S[t + 256], s1);
  atomicAdd(&S[512 + t], q0);
  atomicAdd(&S[512 + t + 256], q1);
}

__global__ void k_bn_fin(float* __restrict__ S, const float* __restrict__ g,
                         const float* __restrict__ be, float* __restrict__ coef) {
  const int d = threadIdx.x;
  const float inv = 1.0f / 8192.0f;
  const float mean = S[d] * inv;
  const float var = S[512 + d] * inv - mean * mean;
  const float a = rsqrtf(var + 1e-5f) * g[d];
  coef[d] = a;
  coef[512 + d] = be[d] - mean * a;
  S[d] = 0.f; S[512 + d] = 0.f;
}

template <int WB>
__global__ __launch_bounds__(256) void k_bn_apply(const float* __restrict__ X, const float* __restrict__ coef,
                                                  float* __restrict__ Yf, u16* __restrict__ Yb) {
  const int n4 = NROW * DD / 4;
  for (int i = blockIdx.x * 256 + threadIdx.x; i < n4; i += gridDim.x * 256) {
    const float4 xv = ((const float4*)X)[i];
    const int d = (i & 127) * 4;
    const float y0 = fmaf(xv.x, coef[d + 0], coef[512 + d + 0]);
    const float y1 = fmaf(xv.y, coef[d + 1], coef[512 + d + 1]);
    const float y2 = fmaf(xv.z, coef[d + 2], coef[512 + d + 2]);
    const float y3 = fmaf(xv.w, coef[d + 3], coef[512 + d + 3]);
    ((float4*)Yf)[i] = make_float4(y0, y1, y2, y3);
    if constexpr (WB) {
      u16x4v o; o[0] = f2b(y0); o[1] = f2b(y1); o[2] = f2b(y2); o[3] = f2b(y3);
      ((u16x4v*)Yb)[i] = o;
    }
  }
}

// ---------------- host launch ----------------
extern "C" void kernel_launch(void* const* d_in, const int* in_sizes, int n_in,
                              void* d_out, int out_size, void* d_ws, size_t ws_size,
                              hipStream_t stream) {
  const float* x    = (const float*)d_in[0];
  const float* emb  = (const float*)d_in[1];
  const float* bn2g = (const float*)d_in[2];
  const float* bn2b = (const float*)d_in[3];
  const float* Wq   = (const float*)d_in[4];
  const float* bq   = (const float*)d_in[5];
  const float* Wk   = (const float*)d_in[6];
  const float* bkp  = (const float*)d_in[7];
  const float* Wv   = (const float*)d_in[8];
  const float* bvp  = (const float*)d_in[9];
  const float* bnag = (const float*)d_in[10];
  const float* bnab = (const float*)d_in[11];
  const float* W1   = (const float*)d_in[12];
  const float* b1   = (const float*)d_in[13];
  const float* W2   = (const float*)d_in[14];
  const float* b2   = (const float*)d_in[15];
  const float* bnfg = (const float*)d_in[16];
  const float* bnfb = (const float*)d_in[17];

  const size_t e_bytes  = (size_t)256 * LL * LL * 2;  // 134 MB bf16 E
  const size_t h1_bytes = (size_t)NROW * FF_ * 2;     // 33.6 MB

  char* p = (char*)d_ws;
  auto alloc = [&](size_t bytes) { char* r = p; p += (bytes + 255) & ~(size_t)255; return r; };
  u16*   xb    = (u16*)alloc((size_t)NROW * DD * 2);
  float* encF  = (float*)alloc((size_t)NROW * DD * 4);
  u16*   encB  = (u16*)alloc((size_t)NROW * DD * 2);
  float* tF    = (float*)alloc((size_t)NROW * DD * 4);
  u16*   qkv   = (u16*)alloc((size_t)3 * NROW * DD * 2); // Q | K | V
  u16*   VT    = (u16*)alloc((size_t)NROW * DD * 2);
  float* Z     = (float*)alloc((size_t)LL * LL * 4);
  float* sums  = (float*)alloc(1024 * 4);
  float* coef  = (float*)alloc(1024 * 4);
  float* bqkv  = (float*)alloc(1536 * 4);
  u16*   embT  = (u16*)alloc((size_t)DD * DD * 2);
  u16*   wqkvT = (u16*)alloc((size_t)3 * DD * DD * 2);
  u16*   w1T   = (u16*)alloc((size_t)DD * FF_ * 2);
  u16*   w2T   = (u16*)alloc((size_t)FF_ * DD * 2);
  const size_t fixed = (size_t)(p - (char*)d_ws);
  const bool useE = (fixed + e_bytes) <= ws_size;   // E aliases h1 (disjoint lifetimes)
  u16* Ebuf = (u16*)alloc(useE ? e_bytes : h1_bytes);
  u16* h1 = Ebuf;
  if ((size_t)(p - (char*)d_ws) > ws_size) return;

  auto run_bn = [&](const float* Xs, const float* g, const float* be, float* Yf, u16* Yb) {
    k_bn_stats<<<256, 256, 0, stream>>>(Xs, sums);
    k_bn_fin<<<1, 512, 0, stream>>>(sums, g, be, coef);
    if (Yb) k_bn_apply<1><<<2048, 256, 0, stream>>>(Xs, coef, Yf, Yb);
    else    k_bn_apply<0><<<2048, 256, 0, stream>>>(Xs, coef, Yf, nullptr);
  };

  k_zero<<<4, 256, 0, stream>>>(sums, 1024);
  k_f32_to_bf16<<<2048, 256, 0, stream>>>(x, xb, NROW * DD / 4);
  k_wtrans<<<dim3(16, 16), 256, 0, stream>>>(emb, embT, DD, DD);
  k_gemm<64, 0, 0, 0, 1, 0, 0><<<dim3(128, 4), 256, 0, stream>>>(xb, embT, nullptr, nullptr, tF, nullptr, DD, DD);
  run_bn(tF, bn2g, bn2b, encF, encB);

  for (int i = 0; i < 3; ++i) {
    k_wtrans<<<dim3(16, 16), 256, 0, stream>>>(Wq + (size_t)i * DD * DD, wqkvT, DD, DD);
    k_wtrans<<<dim3(16, 16), 256, 0, stream>>>(Wk + (size_t)i * DD * DD, wqkvT + (size_t)512 * DD, DD, DD);
    k_wtrans<<<dim3(16, 16), 256, 0, stream>>>(Wv + (size_t)i * DD * DD, wqkvT + (size_t)1024 * DD, DD, DD);
    k_catbias<<<6, 256, 0, stream>>>(bq + i * DD, bkp + i * DD, bvp + i * DD, bqkv);
    k_gemm<128, 1, 1, 0, 0, 1, 1><<<dim3(64, 12), 256, 0, stream>>>(encB, wqkvT, bqkv, nullptr, nullptr, qkv, DD, 1536);
    k_vtrans<<<dim3(256, 8), 256, 0, stream>>>(qkv + 2 * QKVOFF, VT);
    k_zero<<<1024, 256, 0, stream>>>(Z, LL * LL);
    if (useE) {
      k_attn_ze<<<dim3(8, 8, 16), 256, 0, stream>>>(qkv, qkv + QKVOFF, Ebuf, Z);
      k_recip<<<1024, 256, 0, stream>>>(Z, LL * LL);
      k_attn_pv2<<<dim3(256, 4), 256, 0, stream>>>(Ebuf, VT, Z, encF, tF);
    } else {
      k_attn_z<<<dim3(8, 8, 16), 256, 0, stream>>>(qkv, qkv + QKVOFF, Z);
      k_recip<<<1024, 256, 0, stream>>>(Z, LL * LL);
      k_attn_pv<<<dim3(256, 8), 256, 0, stream>>>(qkv, qkv + QKVOFF, VT, Z, encF, tF);
    }
    run_bn(tF, bnag + i * DD, bnab + i * DD, encF, encB);
    k_wtrans<<<dim3(16, 64), 256, 0, stream>>>(W1 + (size_t)i * DD * FF_, w1T, DD, FF_);
    k_gemm<128, 1, 1, 0, 0, 1, 0><<<dim3(64, 16), 256, 0, stream>>>(encB, w1T, b1 + i * FF_, nullptr, nullptr, h1, DD, FF_);
    k_wtrans<<<dim3(64, 16), 256, 0, stream>>>(W2 + (size_t)i * FF_ * DD, w2T, FF_, DD);
    k_gemm<64, 0, 1, 1, 1, 0, 0><<<dim3(128, 4), 256, 0, stream>>>(h1, w2T, b2 + i * DD, encF, tF, nullptr, FF_, DD);
    float* yf = (i == 2) ? (float*)d_out : encF;
    run_bn(tF, bnfg + i * DD, bnfb + i * DD, yf, (i == 2) ? nullptr : encB);
  }
}

// Round 8
// 728.595 us; speedup vs baseline: 1.2317x; 1.2314x over previous
//
#include <hip/hip_runtime.h>

#define DEVI __device__ __forceinline__

typedef unsigned short u16;
typedef __attribute__((ext_vector_type(8))) short s16x8;
typedef __attribute__((ext_vector_type(4))) float f32x4;
typedef __attribute__((ext_vector_type(4))) unsigned short u16x4v;
typedef __attribute__((ext_vector_type(2))) unsigned int u32x2;

constexpr int NB   = 16;
constexpr int LL   = 512;
constexpr int DD   = 512;
constexpr int FF_  = 2048;
constexpr int NROW = NB * LL;                  // 8192
constexpr float C2 = 0.17677669529663687f * 1.4426950408889634f; // scale*log2(e)
constexpr size_t QKVOFF = (size_t)NROW * DD;   // elems per Q/K/V segment

DEVI u16 f2b(float f) {
  unsigned int u = __float_as_uint(f);
  unsigned int r = u + 0x7FFFu + ((u >> 16) & 1u); // RNE
  return (u16)(r >> 16);
}

// async global->LDS, 16B per lane; LDS dest = uniform base + lane*16
DEVI void gload16(const void* g, void* l) {
  __builtin_amdgcn_global_load_lds(
      (const __attribute__((address_space(1))) unsigned int*)(unsigned long long)g,
      (__attribute__((address_space(3))) unsigned int*)(unsigned int)(unsigned long long)l,
      16, 0, 0);
}

// ---------------- elementwise helpers ----------------
__global__ __launch_bounds__(256) void k_f32_to_bf16(const float* __restrict__ X, u16* __restrict__ Y, int n4) {
  for (int i = blockIdx.x * 256 + threadIdx.x; i < n4; i += gridDim.x * 256) {
    float4 x = ((const float4*)X)[i];
    u16x4v o; o[0] = f2b(x.x); o[1] = f2b(x.y); o[2] = f2b(x.z); o[3] = f2b(x.w);
    ((u16x4v*)Y)[i] = o;
  }
}

__global__ __launch_bounds__(256) void k_zero(float* __restrict__ p, int n) {
  int i = blockIdx.x * 256 + threadIdx.x;
  if (i < n) p[i] = 0.f;
}

__global__ __launch_bounds__(256) void k_recip(float* __restrict__ p, int n) {
  int i = blockIdx.x * 256 + threadIdx.x;
  if (i < n) p[i] = 1.0f / p[i];
}

__global__ void k_catbias(const float* __restrict__ a, const float* __restrict__ b,
                          const float* __restrict__ c, float* __restrict__ o) {
  int i = blockIdx.x * 256 + threadIdx.x; // 1536
  o[i] = (i < 512) ? a[i] : (i < 1024) ? b[i - 512] : c[i - 1024];
}

// ---------------- weight transpose + convert: WT[m*K+k] = bf16(W[k*M+m]) ----------------
__global__ __launch_bounds__(256) void k_wtrans(const float* __restrict__ W, u16* __restrict__ WT, int K, int M) {
  __shared__ float tile[32][33];
  const int k0 = blockIdx.x * 32, m0 = blockIdx.y * 32;
  const int tx = threadIdx.x & 31, ty = threadIdx.x >> 5;
#pragma unroll
  for (int j = 0; j < 4; ++j) tile[ty + j * 8][tx] = W[(size_t)(k0 + ty + j * 8) * M + m0 + tx];
  __syncthreads();
#pragma unroll
  for (int j = 0; j < 4; ++j) WT[(size_t)(m0 + ty + j * 8) * K + k0 + tx] = f2b(tile[tx][ty + j * 8]);
}

// ---------------- GEMM (m97 structure): C[row,col] = act(A[row,:].Bt[col,:] + bias) ----------------
template <int BM, int RELU, int HASB, int HASRES, int OUTF, int OUTB, int SPLIT3>
__global__ __launch_bounds__(256) void k_gemm(const u16* __restrict__ A, const u16* __restrict__ Bt,
                                              const float* __restrict__ bias, const float* __restrict__ Res,
                                              float* __restrict__ Cf, u16* __restrict__ Cb,
                                              int K, int Ncols) {
  constexpr int WR = BM / 64;
  constexpr int WC = 4 / WR;
  constexpr int MW = 4;
  constexpr int NW = 128 / (16 * WC);
  __shared__ __align__(16) u16 As[BM * 64];
  __shared__ __align__(16) u16 Bs[128 * 64];
  const int t = threadIdx.x, lane = t & 63, w = t >> 6;
  const int wr = w / WC, wc = w % WC, l16 = lane & 15, lhi = lane >> 4;
  const int row0 = blockIdx.x * BM, col0 = blockIdx.y * 128;
  const int sr = lane >> 3, sc = (lane & 7) * 8;
  const u16* Ag = A + (size_t)(row0 + sr) * K + sc;
  const u16* Bg = Bt + (size_t)(col0 + sr) * K + sc;

  f32x4 acc[MW][NW] = {};

  for (int k0 = 0; k0 < K; k0 += 64) {
    __syncthreads();
#pragma unroll
    for (int j = 0; j < BM / 32; ++j) {
      const int ch = w * (BM / 32) + j;
      gload16(Ag + (size_t)(ch * 8) * K + k0, As + ch * 512);
    }
#pragma unroll
    for (int j = 0; j < 4; ++j) {
      const int ch = w * 4 + j;
      gload16(Bg + (size_t)(ch * 8) * K + k0, Bs + ch * 512);
    }
    __syncthreads();
#pragma unroll
    for (int kk = 0; kk < 2; ++kk) {
      s16x8 af[MW], bfv[NW];
#pragma unroll
      for (int m = 0; m < MW; ++m) af[m] = *(const s16x8*)(As + (wr * 64 + m * 16 + l16) * 64 + kk * 32 + lhi * 8);
#pragma unroll
      for (int n = 0; n < NW; ++n) bfv[n] = *(const s16x8*)(Bs + (wc * (16 * NW) + n * 16 + l16) * 64 + kk * 32 + lhi * 8);
#pragma unroll
      for (int m = 0; m < MW; ++m)
#pragma unroll
        for (int n = 0; n < NW; ++n)
          acc[m][n] = __builtin_amdgcn_mfma_f32_16x16x32_bf16(af[m], bfv[n], acc[m][n], 0, 0, 0);
    }
  }

#pragma unroll
  for (int n = 0; n < NW; ++n) {
    const int col = col0 + wc * (16 * NW) + n * 16 + l16;
    float bv = 0.f;
    if constexpr (HASB) bv = bias[col];
#pragma unroll
    for (int m = 0; m < MW; ++m) {
      const int rbase = row0 + wr * 64 + m * 16 + lhi * 4;
#pragma unroll
      for (int r = 0; r < 4; ++r) {
        float v = acc[m][n][r] + bv;
        if constexpr (RELU) v = fmaxf(v, 0.f);
        const int row = rbase + r;
        const size_t idx = (size_t)row * Ncols + col;
        if constexpr (HASRES) v += Res[idx];
        if constexpr (OUTF) Cf[idx] = v;
        if constexpr (OUTB) {
          if constexpr (SPLIT3) {
            const size_t ib = (size_t)(col >> 9) * QKVOFF + (size_t)row * DD + (col & 511);
            Cb[ib] = f2b(v);
          } else {
            Cb[idx] = f2b(v);
          }
        }
      }
    }
  }
}

// ---------------- attention pass 1: Z[q,k] = sum_n exp(scale * Q_[n,q,:].K_[n,k,:]) ----------------
__global__ __launch_bounds__(256) void k_attn_z(const u16* __restrict__ Q, const u16* __restrict__ Kt,
                                                float* __restrict__ Z) {
  const int t = threadIdx.x, lane = t & 63, w = t >> 6;
  const int l16 = lane & 15, lhi = lane >> 4;
  const int q0 = blockIdx.x * 64 + (w >> 1) * 32;
  const int k0 = blockIdx.y * 64 + (w & 1) * 32;
  const int n0 = blockIdx.z * 16;
  f32x4 zac[2][2] = {};
  for (int nn = 0; nn < 16; ++nn) {
    const int n = n0 + nn, h = n >> 4, b = n & 15;
    const size_t base = (size_t)b * LL * DD + (size_t)h * 32;
    s16x8 a[2], bb[2];
#pragma unroll
    for (int mi = 0; mi < 2; ++mi) a[mi] = *(const s16x8*)(Q + base + (size_t)(q0 + mi * 16 + l16) * DD + lhi * 8);
#pragma unroll
    for (int ni = 0; ni < 2; ++ni) bb[ni] = *(const s16x8*)(Kt + base + (size_t)(k0 + ni * 16 + l16) * DD + lhi * 8);
#pragma unroll
    for (int mi = 0; mi < 2; ++mi)
#pragma unroll
      for (int ni = 0; ni < 2; ++ni) {
        f32x4 z4 = {0.f, 0.f, 0.f, 0.f};
        f32x4 s = __builtin_amdgcn_mfma_f32_16x16x32_bf16(a[mi], bb[ni], z4, 0, 0, 0);
#pragma unroll
        for (int r = 0; r < 4; ++r) zac[mi][ni][r] += exp2f(s[r] * C2);
      }
  }
#pragma unroll
  for (int mi = 0; mi < 2; ++mi)
#pragma unroll
    for (int ni = 0; ni < 2; ++ni)
#pragma unroll
      for (int r = 0; r < 4; ++r)
        atomicAdd(&Z[(q0 + mi * 16 + lhi * 4 + r) * LL + k0 + ni * 16 + l16], zac[mi][ni][r]);
}

// ---------------- attention pass 2 (pv3): one block per n, K/V resident in LDS ----------------
// 512 threads = 8 waves; wave w owns q rows [w*64, w*64+64). K staged to padded [512][40u16] rows,
// V staged WITH transpose to [32][520u16] rows (replaces the separate vtrans kernel).
// After one barrier, each wave sweeps all k from LDS: QK^T (swapped operands) -> exp*IZ ->
// per-wave P transpose buffer -> PV. No inter-wave deps, no further barriers.
__global__ __launch_bounds__(512) void k_attn_pv3(const u16* __restrict__ Q, const u16* __restrict__ K,
                                                  const u16* __restrict__ V, const float* __restrict__ IZ,
                                                  const float* __restrict__ Res, float* __restrict__ T) {
  __shared__ __align__(16) u16 Kl[512 * 40];  // rows padded 32->40 u16: 2-way banks max
  __shared__ __align__(16) u16 Vl[32 * 520];  // d-major rows padded 512->520 u16
  __shared__ __align__(16) u16 Pl[8][1024];   // per-wave P transpose buffer
  const int n = blockIdx.x, h = n >> 4, b = n & 15;
  const int t = threadIdx.x, lane = t & 63, w = t >> 6;
  const int l16 = lane & 15, lhi = lane >> 4;
  const size_t base = (size_t)b * LL * DD + (size_t)h * 32;

  // stage K: 2048 x 16B chunks (4 per thread)
#pragma unroll
  for (int j = 0; j < 4; ++j) {
    const int c = t + j * 512;
    const int k = c >> 2, part = c & 3;
    const s16x8 v = *(const s16x8*)(K + base + (size_t)k * DD + part * 8);
    *(s16x8*)(Kl + k * 40 + part * 8) = v;
  }
  // stage V with in-flight transpose: read 8 d's of one k, scatter into d-rows
#pragma unroll
  for (int j = 0; j < 4; ++j) {
    const int c = t + j * 512;
    const int k = c >> 2, dp = c & 3;
    const s16x8 v = *(const s16x8*)(V + base + (size_t)k * DD + dp * 8);
#pragma unroll
    for (int jj = 0; jj < 8; ++jj) Vl[(dp * 8 + jj) * 520 + k] = (u16)v[jj];
  }
  // preload this wave's 4 Q fragments (global, independent of LDS)
  const int qbase = w * 64;
  s16x8 aqv[4];
#pragma unroll
  for (int qf = 0; qf < 4; ++qf)
    aqv[qf] = *(const s16x8*)(Q + base + (size_t)(qbase + qf * 16 + l16) * DD + lhi * 8);
  __syncthreads();

  char* P = (char*)&Pl[w][0];
  const int wxor = (l16 & 7) << 4;
  const int wbase = l16 * 128 + lhi * 8;

#pragma unroll
  for (int qf = 0; qf < 4; ++qf) {
    const int q16 = qbase + qf * 16;
    const float* izrow = IZ + (size_t)(q16 + l16) * LL + lhi * 4;
    f32x4 oa[2] = {};
#pragma unroll
    for (int kt = 0; kt < 8; ++kt) {
      const int kb = kt * 64;
      f32x4 s[4]; float4 iz[4];
#pragma unroll
      for (int ks = 0; ks < 4; ++ks) {
        const s16x8 af = *(const s16x8*)(Kl + (kb + ks * 16 + l16) * 40 + lhi * 8);
        f32x4 z4 = {0.f, 0.f, 0.f, 0.f};
        s[ks] = __builtin_amdgcn_mfma_f32_16x16x32_bf16(af, aqv[qf], z4, 0, 0, 0);
        iz[ks] = *(const float4*)(izrow + kb + ks * 16);
      }
#pragma unroll
      for (int ks = 0; ks < 4; ++ks) {
        const float p0 = exp2f(s[ks][0] * C2) * iz[ks].x;
        const float p1 = exp2f(s[ks][1] * C2) * iz[ks].y;
        const float p2 = exp2f(s[ks][2] * C2) * iz[ks].z;
        const float p3 = exp2f(s[ks][3] * C2) * iz[ks].w;
        unsigned int pk0, pk1;
        asm("v_cvt_pk_bf16_f32 %0, %1, %2" : "=v"(pk0) : "v"(p0), "v"(p1));
        asm("v_cvt_pk_bf16_f32 %0, %1, %2" : "=v"(pk1) : "v"(p2), "v"(p3));
        u32x2 pw; pw[0] = pk0; pw[1] = pk1;
        *(u32x2*)(P + ((wbase + ks * 32) ^ wxor)) = pw;
      }
#pragma unroll
      for (int kc = 0; kc < 2; ++kc) {
        const s16x8 pa = *(const s16x8*)(P + ((l16 * 128 + kc * 64 + lhi * 16) ^ wxor));
#pragma unroll
        for (int dt = 0; dt < 2; ++dt) {
          const s16x8 bv = *(const s16x8*)(Vl + (dt * 16 + l16) * 520 + kb + kc * 32 + lhi * 8);
          oa[dt] = __builtin_amdgcn_mfma_f32_16x16x32_bf16(pa, bv, oa[dt], 0, 0, 0);
        }
      }
    }
#pragma unroll
    for (int dt = 0; dt < 2; ++dt)
#pragma unroll
      for (int r = 0; r < 4; ++r) {
        const size_t idx = (size_t)(b * LL + q16 + lhi * 4 + r) * DD + h * 32 + dt * 16 + l16;
        T[idx] = oa[dt][r] + Res[idx];
      }
  }
}

// ---------------- BatchNorm ----------------
__global__ __launch_bounds__(256) void k_bn_stats(const float* __restrict__ X, float* __restrict__ S) {
  const int t = threadIdx.x;
  const int r0 = blockIdx.x * 32;
  float s0 = 0.f, q0 = 0.f, s1 = 0.f, q1 = 0.f;
  for (int r = 0; r < 32; ++r) {
    const float x0 = X[(size_t)(r0 + r) * DD + t];
    const float x1 = X[(size_t)(r0 + r) * DD + t + 256];
    s0 += x0; q0 += x0 * x0; s1 += x1; q1 += x1 * x1;
  }
  atomicAdd(&S[t], s0);
  atomicAdd(&S[t + 256], s1);
  atomicAdd(&S[512 + t], q0);
  atomicAdd(&S[512 + t + 256], q1);
}

__global__ void k_bn_fin(float* __restrict__ S, const float* __restrict__ g,
                         const float* __restrict__ be, float* __restrict__ coef) {
  const int d = threadIdx.x;
  const float inv = 1.0f / 8192.0f;
  const float mean = S[d] * inv;
  const float var = S[512 + d] * inv - mean * mean;
  const float a = rsqrtf(var + 1e-5f) * g[d];
  coef[d] = a;
  coef[512 + d] = be[d] - mean * a;
  S[d] = 0.f; S[512 + d] = 0.f;
}

template <int WB>
__global__ __launch_bounds__(256) void k_bn_apply(const float* __restrict__ X, const float* __restrict__ coef,
                                                  float* __restrict__ Yf, u16* __restrict__ Yb) {
  const int n4 = NROW * DD / 4;
  for (int i = blockIdx.x * 256 + threadIdx.x; i < n4; i += gridDim.x * 256) {
    const float4 xv = ((const float4*)X)[i];
    const int d = (i & 127) * 4;
    const float y0 = fmaf(xv.x, coef[d + 0], coef[512 + d + 0]);
    const float y1 = fmaf(xv.y, coef[d + 1], coef[512 + d + 1]);
    const float y2 = fmaf(xv.z, coef[d + 2], coef[512 + d + 2]);
    const float y3 = fmaf(xv.w, coef[d + 3], coef[512 + d + 3]);
    ((float4*)Yf)[i] = make_float4(y0, y1, y2, y3);
    if constexpr (WB) {
      u16x4v o; o[0] = f2b(y0); o[1] = f2b(y1); o[2] = f2b(y2); o[3] = f2b(y3);
      ((u16x4v*)Yb)[i] = o;
    }
  }
}

// ---------------- host launch ----------------
extern "C" void kernel_launch(void* const* d_in, const int* in_sizes, int n_in,
                              void* d_out, int out_size, void* d_ws, size_t ws_size,
                              hipStream_t stream) {
  const float* x    = (const float*)d_in[0];
  const float* emb  = (const float*)d_in[1];
  const float* bn2g = (const float*)d_in[2];
  const float* bn2b = (const float*)d_in[3];
  const float* Wq   = (const float*)d_in[4];
  const float* bq   = (const float*)d_in[5];
  const float* Wk   = (const float*)d_in[6];
  const float* bkp  = (const float*)d_in[7];
  const float* Wv   = (const float*)d_in[8];
  const float* bvp  = (const float*)d_in[9];
  const float* bnag = (const float*)d_in[10];
  const float* bnab = (const float*)d_in[11];
  const float* W1   = (const float*)d_in[12];
  const float* b1   = (const float*)d_in[13];
  const float* W2   = (const float*)d_in[14];
  const float* b2   = (const float*)d_in[15];
  const float* bnfg = (const float*)d_in[16];
  const float* bnfb = (const float*)d_in[17];

  char* p = (char*)d_ws;
  auto alloc = [&](size_t bytes) { char* r = p; p += (bytes + 255) & ~(size_t)255; return r; };
  u16*   xb    = (u16*)alloc((size_t)NROW * DD * 2);
  float* encF  = (float*)alloc((size_t)NROW * DD * 4);
  u16*   encB  = (u16*)alloc((size_t)NROW * DD * 2);
  float* tF    = (float*)alloc((size_t)NROW * DD * 4);
  u16*   qkv   = (u16*)alloc((size_t)3 * NROW * DD * 2); // Q | K | V
  u16*   h1    = (u16*)alloc((size_t)NROW * FF_ * 2);
  float* Z     = (float*)alloc((size_t)LL * LL * 4);
  float* sums  = (float*)alloc(1024 * 4);
  float* coef  = (float*)alloc(1024 * 4);
  float* bqkv  = (float*)alloc(1536 * 4);
  u16*   embT  = (u16*)alloc((size_t)DD * DD * 2);
  u16*   wqkvT = (u16*)alloc((size_t)3 * DD * DD * 2);
  u16*   w1T   = (u16*)alloc((size_t)DD * FF_ * 2);
  u16*   w2T   = (u16*)alloc((size_t)FF_ * DD * 2);
  if ((size_t)(p - (char*)d_ws) > ws_size) return;

  auto run_bn = [&](const float* Xs, const float* g, const float* be, float* Yf, u16* Yb) {
    k_bn_stats<<<256, 256, 0, stream>>>(Xs, sums);
    k_bn_fin<<<1, 512, 0, stream>>>(sums, g, be, coef);
    if (Yb) k_bn_apply<1><<<2048, 256, 0, stream>>>(Xs, coef, Yf, Yb);
    else    k_bn_apply<0><<<2048, 256, 0, stream>>>(Xs, coef, Yf, nullptr);
  };

  k_zero<<<4, 256, 0, stream>>>(sums, 1024);
  k_f32_to_bf16<<<2048, 256, 0, stream>>>(x, xb, NROW * DD / 4);
  k_wtrans<<<dim3(16, 16), 256, 0, stream>>>(emb, embT, DD, DD);
  k_gemm<64, 0, 0, 0, 1, 0, 0><<<dim3(128, 4), 256, 0, stream>>>(xb, embT, nullptr, nullptr, tF, nullptr, DD, DD);
  run_bn(tF, bn2g, bn2b, encF, encB);

  for (int i = 0; i < 3; ++i) {
    k_wtrans<<<dim3(16, 16), 256, 0, stream>>>(Wq + (size_t)i * DD * DD, wqkvT, DD, DD);
    k_wtrans<<<dim3(16, 16), 256, 0, stream>>>(Wk + (size_t)i * DD * DD, wqkvT + (size_t)512 * DD, DD, DD);
    k_wtrans<<<dim3(16, 16), 256, 0, stream>>>(Wv + (size_t)i * DD * DD, wqkvT + (size_t)1024 * DD, DD, DD);
    k_catbias<<<6, 256, 0, stream>>>(bq + i * DD, bkp + i * DD, bvp + i * DD, bqkv);
    k_gemm<128, 1, 1, 0, 0, 1, 1><<<dim3(64, 12), 256, 0, stream>>>(encB, wqkvT, bqkv, nullptr, nullptr, qkv, DD, 1536);
    k_zero<<<1024, 256, 0, stream>>>(Z, LL * LL);
    k_attn_z<<<dim3(8, 8, 16), 256, 0, stream>>>(qkv, qkv + QKVOFF, Z);
    k_recip<<<1024, 256, 0, stream>>>(Z, LL * LL);
    k_attn_pv3<<<256, 512, 0, stream>>>(qkv, qkv + QKVOFF, qkv + 2 * QKVOFF, Z, encF, tF);
    run_bn(tF, bnag + i * DD, bnab + i * DD, encF, encB);
    k_wtrans<<<dim3(16, 64), 256, 0, stream>>>(W1 + (size_t)i * DD * FF_, w1T, DD, FF_);
    k_gemm<128, 1, 1, 0, 0, 1, 0><<<dim3(64, 16), 256, 0, stream>>>(encB, w1T, b1 + i * FF_, nullptr, nullptr, h1, DD, FF_);
    k_wtrans<<<dim3(64, 16), 256, 0, stream>>>(W2 + (size_t)i * FF_ * DD, w2T, FF_, DD);
    k_gemm<64, 0, 1, 1, 1, 0, 0><<<dim3(128, 4), 256, 0, stream>>>(h1, w2T, b2 + i * DD, encF, tF, nullptr, FF_, DD);
    float* yf = (i == 2) ? (float*)d_out : encF;
    run_bn(tF, bnfg + i * DD, bnfb + i * DD, yf, (i == 2) ? nullptr : encB);
  }
}

// Round 9
// 717.366 us; speedup vs baseline: 1.2510x; 1.0157x over previous
//
#include <hip/hip_runtime.h>

#define DEVI __device__ __forceinline__

typedef unsigned short u16;
typedef __attribute__((ext_vector_type(8))) short s16x8;
typedef __attribute__((ext_vector_type(4))) float f32x4;
typedef __attribute__((ext_vector_type(4))) unsigned short u16x4v;
typedef __attribute__((ext_vector_type(2))) unsigned int u32x2;

constexpr int NB   = 16;
constexpr int LL   = 512;
constexpr int DD   = 512;
constexpr int FF_  = 2048;
constexpr int NROW = NB * LL;                  // 8192
constexpr float C2 = 0.17677669529663687f * 1.4426950408889634f; // scale*log2(e)
constexpr size_t QKVOFF = (size_t)NROW * DD;   // elems per Q/K/V segment

DEVI u16 f2b(float f) {
  unsigned int u = __float_as_uint(f);
  unsigned int r = u + 0x7FFFu + ((u >> 16) & 1u); // RNE
  return (u16)(r >> 16);
}

// async global->LDS, 16B per lane; LDS dest = uniform base + lane*16
DEVI void gload16(const void* g, void* l) {
  __builtin_amdgcn_global_load_lds(
      (const __attribute__((address_space(1))) unsigned int*)(unsigned long long)g,
      (__attribute__((address_space(3))) unsigned int*)(unsigned int)(unsigned long long)l,
      16, 0, 0);
}

// ---------------- elementwise helpers ----------------
__global__ __launch_bounds__(256) void k_f32_to_bf16(const float* __restrict__ X, u16* __restrict__ Y, int n4) {
  for (int i = blockIdx.x * 256 + threadIdx.x; i < n4; i += gridDim.x * 256) {
    float4 x = ((const float4*)X)[i];
    u16x4v o; o[0] = f2b(x.x); o[1] = f2b(x.y); o[2] = f2b(x.z); o[3] = f2b(x.w);
    ((u16x4v*)Y)[i] = o;
  }
}

__global__ __launch_bounds__(256) void k_zero(float* __restrict__ p, int n) {
  int i = blockIdx.x * 256 + threadIdx.x;
  if (i < n) p[i] = 0.f;
}

__global__ __launch_bounds__(256) void k_recip(float* __restrict__ p, int n) {
  int i = blockIdx.x * 256 + threadIdx.x;
  if (i < n) p[i] = 1.0f / p[i];
}

__global__ void k_catbias(const float* __restrict__ a, const float* __restrict__ b,
                          const float* __restrict__ c, float* __restrict__ o) {
  int i = blockIdx.x * 256 + threadIdx.x; // 1536
  o[i] = (i < 512) ? a[i] : (i < 1024) ? b[i - 512] : c[i - 1024];
}

// ---------------- weight transpose + convert: WT[m*K+k] = bf16(W[k*M+m]) ----------------
__global__ __launch_bounds__(256) void k_wtrans(const float* __restrict__ W, u16* __restrict__ WT, int K, int M) {
  __shared__ float tile[32][33];
  const int k0 = blockIdx.x * 32, m0 = blockIdx.y * 32;
  const int tx = threadIdx.x & 31, ty = threadIdx.x >> 5;
#pragma unroll
  for (int j = 0; j < 4; ++j) tile[ty + j * 8][tx] = W[(size_t)(k0 + ty + j * 8) * M + m0 + tx];
  __syncthreads();
#pragma unroll
  for (int j = 0; j < 4; ++j) WT[(size_t)(m0 + ty + j * 8) * K + k0 + tx] = f2b(tile[tx][ty + j * 8]);
}

// ---------------- GEMM (m97 structure): C[row,col] = act(A[row,:].Bt[col,:] + bias) ----------------
// STATS: per-lane (sum,sumsq) over owned rows -> shfl_xor(16,32) reduce over lhi -> 1 atomic/col/wave.
template <int BM, int RELU, int HASB, int HASRES, int OUTF, int OUTB, int STATS, int SPLIT3>
__global__ __launch_bounds__(256) void k_gemm(const u16* __restrict__ A, const u16* __restrict__ Bt,
                                              const float* __restrict__ bias, const float* __restrict__ Res,
                                              float* __restrict__ Cf, u16* __restrict__ Cb,
                                              float* __restrict__ stats, int K, int Ncols) {
  constexpr int WR = BM / 64;
  constexpr int WC = 4 / WR;
  constexpr int MW = 4;
  constexpr int NW = 128 / (16 * WC);
  __shared__ __align__(16) u16 As[BM * 64];
  __shared__ __align__(16) u16 Bs[128 * 64];
  const int t = threadIdx.x, lane = t & 63, w = t >> 6;
  const int wr = w / WC, wc = w % WC, l16 = lane & 15, lhi = lane >> 4;
  const int row0 = blockIdx.x * BM, col0 = blockIdx.y * 128;
  const int sr = lane >> 3, sc = (lane & 7) * 8;
  const u16* Ag = A + (size_t)(row0 + sr) * K + sc;
  const u16* Bg = Bt + (size_t)(col0 + sr) * K + sc;

  f32x4 acc[MW][NW] = {};

  for (int k0 = 0; k0 < K; k0 += 64) {
    __syncthreads();
#pragma unroll
    for (int j = 0; j < BM / 32; ++j) {
      const int ch = w * (BM / 32) + j;
      gload16(Ag + (size_t)(ch * 8) * K + k0, As + ch * 512);
    }
#pragma unroll
    for (int j = 0; j < 4; ++j) {
      const int ch = w * 4 + j;
      gload16(Bg + (size_t)(ch * 8) * K + k0, Bs + ch * 512);
    }
    __syncthreads();
#pragma unroll
    for (int kk = 0; kk < 2; ++kk) {
      s16x8 af[MW], bfv[NW];
#pragma unroll
      for (int m = 0; m < MW; ++m) af[m] = *(const s16x8*)(As + (wr * 64 + m * 16 + l16) * 64 + kk * 32 + lhi * 8);
#pragma unroll
      for (int n = 0; n < NW; ++n) bfv[n] = *(const s16x8*)(Bs + (wc * (16 * NW) + n * 16 + l16) * 64 + kk * 32 + lhi * 8);
#pragma unroll
      for (int m = 0; m < MW; ++m)
#pragma unroll
        for (int n = 0; n < NW; ++n)
          acc[m][n] = __builtin_amdgcn_mfma_f32_16x16x32_bf16(af[m], bfv[n], acc[m][n], 0, 0, 0);
    }
  }

#pragma unroll
  for (int n = 0; n < NW; ++n) {
    const int col = col0 + wc * (16 * NW) + n * 16 + l16;
    float bv = 0.f;
    if constexpr (HASB) bv = bias[col];
    float ssum = 0.f, ssq = 0.f;
#pragma unroll
    for (int m = 0; m < MW; ++m) {
      const int rbase = row0 + wr * 64 + m * 16 + lhi * 4;
#pragma unroll
      for (int r = 0; r < 4; ++r) {
        float v = acc[m][n][r] + bv;
        if constexpr (RELU) v = fmaxf(v, 0.f);
        const int row = rbase + r;
        const size_t idx = (size_t)row * Ncols + col;
        if constexpr (HASRES) v += Res[idx];
        if constexpr (OUTF) Cf[idx] = v;
        if constexpr (OUTB) {
          if constexpr (SPLIT3) {
            const size_t ib = (size_t)(col >> 9) * QKVOFF + (size_t)row * DD + (col & 511);
            Cb[ib] = f2b(v);
          } else {
            Cb[idx] = f2b(v);
          }
        }
        if constexpr (STATS) { ssum += v; ssq += v * v; }
      }
    }
    if constexpr (STATS) {
      // reduce over lhi axis (lanes l16, l16+16, l16+32, l16+48) -> lane lhi==0 holds col total
      ssum += __shfl_xor(ssum, 16); ssq += __shfl_xor(ssq, 16);
      ssum += __shfl_xor(ssum, 32); ssq += __shfl_xor(ssq, 32);
      if (lhi == 0) {
        atomicAdd(&stats[col], ssum);
        atomicAdd(&stats[512 + col], ssq);
      }
    }
  }
}

// ---------------- attention pass 1: Z[q,k] = sum_n exp(scale * Q_[n,q,:].K_[n,k,:]) ----------------
__global__ __launch_bounds__(256) void k_attn_z(const u16* __restrict__ Q, const u16* __restrict__ Kt,
                                                float* __restrict__ Z) {
  const int t = threadIdx.x, lane = t & 63, w = t >> 6;
  const int l16 = lane & 15, lhi = lane >> 4;
  const int q0 = blockIdx.x * 64 + (w >> 1) * 32;
  const int k0 = blockIdx.y * 64 + (w & 1) * 32;
  const int n0 = blockIdx.z * 16;
  f32x4 zac[2][2] = {};
  for (int nn = 0; nn < 16; ++nn) {
    const int n = n0 + nn, h = n >> 4, b = n & 15;
    const size_t base = (size_t)b * LL * DD + (size_t)h * 32;
    s16x8 a[2], bb[2];
#pragma unroll
    for (int mi = 0; mi < 2; ++mi) a[mi] = *(const s16x8*)(Q + base + (size_t)(q0 + mi * 16 + l16) * DD + lhi * 8);
#pragma unroll
    for (int ni = 0; ni < 2; ++ni) bb[ni] = *(const s16x8*)(Kt + base + (size_t)(k0 + ni * 16 + l16) * DD + lhi * 8);
#pragma unroll
    for (int mi = 0; mi < 2; ++mi)
#pragma unroll
      for (int ni = 0; ni < 2; ++ni) {
        f32x4 z4 = {0.f, 0.f, 0.f, 0.f};
        f32x4 s = __builtin_amdgcn_mfma_f32_16x16x32_bf16(a[mi], bb[ni], z4, 0, 0, 0);
#pragma unroll
        for (int r = 0; r < 4; ++r) zac[mi][ni][r] += exp2f(s[r] * C2);
      }
  }
#pragma unroll
  for (int mi = 0; mi < 2; ++mi)
#pragma unroll
    for (int ni = 0; ni < 2; ++ni)
#pragma unroll
      for (int r = 0; r < 4; ++r)
        atomicAdd(&Z[(q0 + mi * 16 + lhi * 4 + r) * LL + k0 + ni * 16 + l16], zac[mi][ni][r]);
}

// ---------------- attention pass 2 (pv3): one block per n, K/V resident in LDS, fused BN stats ----------------
__global__ __launch_bounds__(512) void k_attn_pv3(const u16* __restrict__ Q, const u16* __restrict__ K,
                                                  const u16* __restrict__ V, const float* __restrict__ IZ,
                                                  const float* __restrict__ Res, float* __restrict__ T,
                                                  float* __restrict__ stats) {
  __shared__ __align__(16) u16 Kl[512 * 40];  // rows padded 32->40 u16: 2-way banks max
  __shared__ __align__(16) u16 Vl[32 * 520];  // d-major rows padded 512->520 u16
  __shared__ __align__(16) u16 Pl[8][1024];   // per-wave P transpose buffer
  const int n = blockIdx.x, h = n >> 4, b = n & 15;
  const int t = threadIdx.x, lane = t & 63, w = t >> 6;
  const int l16 = lane & 15, lhi = lane >> 4;
  const size_t base = (size_t)b * LL * DD + (size_t)h * 32;

  // stage K: 2048 x 16B chunks (4 per thread)
#pragma unroll
  for (int j = 0; j < 4; ++j) {
    const int c = t + j * 512;
    const int k = c >> 2, part = c & 3;
    const s16x8 v = *(const s16x8*)(K + base + (size_t)k * DD + part * 8);
    *(s16x8*)(Kl + k * 40 + part * 8) = v;
  }
  // stage V with in-flight transpose
#pragma unroll
  for (int j = 0; j < 4; ++j) {
    const int c = t + j * 512;
    const int k = c >> 2, dp = c & 3;
    const s16x8 v = *(const s16x8*)(V + base + (size_t)k * DD + dp * 8);
#pragma unroll
    for (int jj = 0; jj < 8; ++jj) Vl[(dp * 8 + jj) * 520 + k] = (u16)v[jj];
  }
  // preload this wave's 4 Q fragments
  const int qbase = w * 64;
  s16x8 aqv[4];
#pragma unroll
  for (int qf = 0; qf < 4; ++qf)
    aqv[qf] = *(const s16x8*)(Q + base + (size_t)(qbase + qf * 16 + l16) * DD + lhi * 8);
  __syncthreads();

  char* P = (char*)&Pl[w][0];
  const int wxor = (l16 & 7) << 4;
  const int wbase = l16 * 128 + lhi * 8;
  float ssum[2] = {0.f, 0.f}, ssq[2] = {0.f, 0.f};

#pragma unroll
  for (int qf = 0; qf < 4; ++qf) {
    const int q16 = qbase + qf * 16;
    const float* izrow = IZ + (size_t)(q16 + l16) * LL + lhi * 4;
    f32x4 oa[2] = {};
#pragma unroll
    for (int kt = 0; kt < 8; ++kt) {
      const int kb = kt * 64;
      f32x4 s[4]; float4 iz[4];
#pragma unroll
      for (int ks = 0; ks < 4; ++ks) {
        const s16x8 af = *(const s16x8*)(Kl + (kb + ks * 16 + l16) * 40 + lhi * 8);
        f32x4 z4 = {0.f, 0.f, 0.f, 0.f};
        s[ks] = __builtin_amdgcn_mfma_f32_16x16x32_bf16(af, aqv[qf], z4, 0, 0, 0);
        iz[ks] = *(const float4*)(izrow + kb + ks * 16);
      }
#pragma unroll
      for (int ks = 0; ks < 4; ++ks) {
        const float p0 = exp2f(s[ks][0] * C2) * iz[ks].x;
        const float p1 = exp2f(s[ks][1] * C2) * iz[ks].y;
        const float p2 = exp2f(s[ks][2] * C2) * iz[ks].z;
        const float p3 = exp2f(s[ks][3] * C2) * iz[ks].w;
        unsigned int pk0, pk1;
        asm("v_cvt_pk_bf16_f32 %0, %1, %2" : "=v"(pk0) : "v"(p0), "v"(p1));
        asm("v_cvt_pk_bf16_f32 %0, %1, %2" : "=v"(pk1) : "v"(p2), "v"(p3));
        u32x2 pw; pw[0] = pk0; pw[1] = pk1;
        *(u32x2*)(P + ((wbase + ks * 32) ^ wxor)) = pw;
      }
#pragma unroll
      for (int kc = 0; kc < 2; ++kc) {
        const s16x8 pa = *(const s16x8*)(P + ((l16 * 128 + kc * 64 + lhi * 16) ^ wxor));
#pragma unroll
        for (int dt = 0; dt < 2; ++dt) {
          const s16x8 bv = *(const s16x8*)(Vl + (dt * 16 + l16) * 520 + kb + kc * 32 + lhi * 8);
          oa[dt] = __builtin_amdgcn_mfma_f32_16x16x32_bf16(pa, bv, oa[dt], 0, 0, 0);
        }
      }
    }
#pragma unroll
    for (int dt = 0; dt < 2; ++dt)
#pragma unroll
      for (int r = 0; r < 4; ++r) {
        const size_t idx = (size_t)(b * LL + q16 + lhi * 4 + r) * DD + h * 32 + dt * 16 + l16;
        const float v = oa[dt][r] + Res[idx];
        T[idx] = v;
        ssum[dt] += v; ssq[dt] += v * v;
      }
  }
#pragma unroll
  for (int dt = 0; dt < 2; ++dt) {
    float su = ssum[dt], sq = ssq[dt];
    su += __shfl_xor(su, 16); sq += __shfl_xor(sq, 16);
    su += __shfl_xor(su, 32); sq += __shfl_xor(sq, 32);
    if (lhi == 0) {
      const int col = h * 32 + dt * 16 + l16;
      atomicAdd(&stats[col], su);
      atomicAdd(&stats[512 + col], sq);
    }
  }
}

// ---------------- BatchNorm finalize + apply (stats are producer-fused) ----------------
__global__ void k_bn_fin(float* __restrict__ S, const float* __restrict__ g,
                         const float* __restrict__ be, float* __restrict__ coef) {
  const int d = threadIdx.x;
  const float inv = 1.0f / 8192.0f;
  const float mean = S[d] * inv;
  const float var = S[512 + d] * inv - mean * mean;
  const float a = rsqrtf(var + 1e-5f) * g[d];
  coef[d] = a;
  coef[512 + d] = be[d] - mean * a;
  S[d] = 0.f; S[512 + d] = 0.f;
}

template <int WB>
__global__ __launch_bounds__(256) void k_bn_apply(const float* __restrict__ X, const float* __restrict__ coef,
                                                  float* __restrict__ Yf, u16* __restrict__ Yb) {
  const int n4 = NROW * DD / 4;
  for (int i = blockIdx.x * 256 + threadIdx.x; i < n4; i += gridDim.x * 256) {
    const float4 xv = ((const float4*)X)[i];
    const int d = (i & 127) * 4;
    const float y0 = fmaf(xv.x, coef[d + 0], coef[512 + d + 0]);
    const float y1 = fmaf(xv.y, coef[d + 1], coef[512 + d + 1]);
    const float y2 = fmaf(xv.z, coef[d + 2], coef[512 + d + 2]);
    const float y3 = fmaf(xv.w, coef[d + 3], coef[512 + d + 3]);
    ((float4*)Yf)[i] = make_float4(y0, y1, y2, y3);
    if constexpr (WB) {
      u16x4v o; o[0] = f2b(y0); o[1] = f2b(y1); o[2] = f2b(y2); o[3] = f2b(y3);
      ((u16x4v*)Yb)[i] = o;
    }
  }
}

// ---------------- host launch ----------------
extern "C" void kernel_launch(void* const* d_in, const int* in_sizes, int n_in,
                              void* d_out, int out_size, void* d_ws, size_t ws_size,
                              hipStream_t stream) {
  const float* x    = (const float*)d_in[0];
  const float* emb  = (const float*)d_in[1];
  const float* bn2g = (const float*)d_in[2];
  const float* bn2b = (const float*)d_in[3];
  const float* Wq   = (const float*)d_in[4];
  const float* bq   = (const float*)d_in[5];
  const float* Wk   = (const float*)d_in[6];
  const float* bkp  = (const float*)d_in[7];
  const float* Wv   = (const float*)d_in[8];
  const float* bvp  = (const float*)d_in[9];
  const float* bnag = (const float*)d_in[10];
  const float* bnab = (const float*)d_in[11];
  const float* W1   = (const float*)d_in[12];
  const float* b1   = (const float*)d_in[13];
  const float* W2   = (const float*)d_in[14];
  const float* b2   = (const float*)d_in[15];
  const float* bnfg = (const float*)d_in[16];
  const float* bnfb = (const float*)d_in[17];

  char* p = (char*)d_ws;
  auto alloc = [&](size_t bytes) { char* r = p; p += (bytes + 255) & ~(size_t)255; return r; };
  u16*   xb    = (u16*)alloc((size_t)NROW * DD * 2);
  float* encF  = (float*)alloc((size_t)NROW * DD * 4);
  u16*   encB  = (u16*)alloc((size_t)NROW * DD * 2);
  float* tF    = (float*)alloc((size_t)NROW * DD * 4);
  u16*   qkv   = (u16*)alloc((size_t)3 * NROW * DD * 2); // Q | K | V
  u16*   h1    = (u16*)alloc((size_t)NROW * FF_ * 2);
  float* Z     = (float*)alloc((size_t)LL * LL * 4);
  float* sums  = (float*)alloc(1024 * 4);
  float* coef  = (float*)alloc(1024 * 4);
  float* bqkv  = (float*)alloc(1536 * 4);
  u16*   embT  = (u16*)alloc((size_t)DD * DD * 2);
  u16*   wqkvT = (u16*)alloc((size_t)3 * DD * DD * 2);
  u16*   w1T   = (u16*)alloc((size_t)DD * FF_ * 2);
  u16*   w2T   = (u16*)alloc((size_t)FF_ * DD * 2);
  if ((size_t)(p - (char*)d_ws) > ws_size) return;

  auto run_bn = [&](const float* Xs, const float* g, const float* be, float* Yf, u16* Yb) {
    k_bn_fin<<<1, 512, 0, stream>>>(sums, g, be, coef);
    if (Yb) k_bn_apply<1><<<2048, 256, 0, stream>>>(Xs, coef, Yf, Yb);
    else    k_bn_apply<0><<<2048, 256, 0, stream>>>(Xs, coef, Yf, nullptr);
  };

  k_zero<<<4, 256, 0, stream>>>(sums, 1024);
  k_f32_to_bf16<<<2048, 256, 0, stream>>>(x, xb, NROW * DD / 4);
  k_wtrans<<<dim3(16, 16), 256, 0, stream>>>(emb, embT, DD, DD);
  // emb conv (no bias), BM=128, fused stats
  k_gemm<128, 0, 0, 0, 1, 0, 1, 0><<<dim3(64, 4), 256, 0, stream>>>(xb, embT, nullptr, nullptr, tF, nullptr, sums, DD, DD);
  run_bn(tF, bn2g, bn2b, encF, encB);

  for (int i = 0; i < 3; ++i) {
    k_wtrans<<<dim3(16, 16), 256, 0, stream>>>(Wq + (size_t)i * DD * DD, wqkvT, DD, DD);
    k_wtrans<<<dim3(16, 16), 256, 0, stream>>>(Wk + (size_t)i * DD * DD, wqkvT + (size_t)512 * DD, DD, DD);
    k_wtrans<<<dim3(16, 16), 256, 0, stream>>>(Wv + (size_t)i * DD * DD, wqkvT + (size_t)1024 * DD, DD, DD);
    k_catbias<<<6, 256, 0, stream>>>(bq + i * DD, bkp + i * DD, bvp + i * DD, bqkv);
    k_gemm<128, 1, 1, 0, 0, 1, 0, 1><<<dim3(64, 12), 256, 0, stream>>>(encB, wqkvT, bqkv, nullptr, nullptr, qkv, nullptr, DD, 1536);
    k_zero<<<1024, 256, 0, stream>>>(Z, LL * LL);
    k_attn_z<<<dim3(8, 8, 16), 256, 0, stream>>>(qkv, qkv + QKVOFF, Z);
    k_recip<<<1024, 256, 0, stream>>>(Z, LL * LL);
    k_attn_pv3<<<256, 512, 0, stream>>>(qkv, qkv + QKVOFF, qkv + 2 * QKVOFF, Z, encF, tF, sums);
    run_bn(tF, bnag + i * DD, bnab + i * DD, encF, encB);
    k_wtrans<<<dim3(16, 64), 256, 0, stream>>>(W1 + (size_t)i * DD * FF_, w1T, DD, FF_);
    k_gemm<128, 1, 1, 0, 0, 1, 0, 0><<<dim3(64, 16), 256, 0, stream>>>(encB, w1T, b1 + i * FF_, nullptr, nullptr, h1, nullptr, DD, FF_);
    k_wtrans<<<dim3(64, 16), 256, 0, stream>>>(W2 + (size_t)i * FF_ * DD, w2T, FF_, DD);
    // FF2: BM=128, fused stats
    k_gemm<128, 0, 1, 1, 1, 0, 1, 0><<<dim3(64, 4), 256, 0, stream>>>(h1, w2T, b2 + i * DD, encF, tF, nullptr, sums, FF_, DD);
    float* yf = (i == 2) ? (float*)d_out : encF;
    run_bn(tF, bnfg + i * DD, bnfb + i * DD, yf, (i == 2) ? nullptr : encB);
  }
}

// Round 10
// 673.608 us; speedup vs baseline: 1.3323x; 1.0650x over previous
//
#include <hip/hip_runtime.h>

#define DEVI __device__ __forceinline__

typedef unsigned short u16;
typedef __attribute__((ext_vector_type(8))) short s16x8;
typedef __attribute__((ext_vector_type(4))) float f32x4;
typedef __attribute__((ext_vector_type(4))) unsigned short u16x4v;
typedef __attribute__((ext_vector_type(2))) unsigned int u32x2;

constexpr int NB   = 16;
constexpr int LL   = 512;
constexpr int DD   = 512;
constexpr int FF_  = 2048;
constexpr int NROW = NB * LL;                  // 8192
constexpr float C2 = 0.17677669529663687f * 1.4426950408889634f; // scale*log2(e)
constexpr size_t QKVOFF = (size_t)NROW * DD;   // elems per Q/K/V segment

DEVI u16 f2b(float f) {
  unsigned int u = __float_as_uint(f);
  unsigned int r = u + 0x7FFFu + ((u >> 16) & 1u); // RNE
  return (u16)(r >> 16);
}

// async global->LDS, 16B per lane; LDS dest = uniform base + lane*16
DEVI void gload16(const void* g, void* l) {
  __builtin_amdgcn_global_load_lds(
      (const __attribute__((address_space(1))) unsigned int*)(unsigned long long)g,
      (__attribute__((address_space(3))) unsigned int*)(unsigned int)(unsigned long long)l,
      16, 0, 0);
}

// ---------------- elementwise helpers ----------------
__global__ __launch_bounds__(256) void k_f32_to_bf16(const float* __restrict__ X, u16* __restrict__ Y, int n4) {
  for (int i = blockIdx.x * 256 + threadIdx.x; i < n4; i += gridDim.x * 256) {
    float4 x = ((const float4*)X)[i];
    u16x4v o; o[0] = f2b(x.x); o[1] = f2b(x.y); o[2] = f2b(x.z); o[3] = f2b(x.w);
    ((u16x4v*)Y)[i] = o;
  }
}

__global__ __launch_bounds__(256) void k_zero(float* __restrict__ p, int n) {
  int i = blockIdx.x * 256 + threadIdx.x;
  if (i < n) p[i] = 0.f;
}

__global__ __launch_bounds__(256) void k_recip(float* __restrict__ p, int n) {
  int i = blockIdx.x * 256 + threadIdx.x;
  if (i < n) p[i] = 1.0f / p[i];
}

__global__ void k_catbias(const float* __restrict__ a, const float* __restrict__ b,
                          const float* __restrict__ c, float* __restrict__ o) {
  int i = blockIdx.x * 256 + threadIdx.x; // 1536
  o[i] = (i < 512) ? a[i] : (i < 1024) ? b[i - 512] : c[i - 1024];
}

// ---------------- weight transpose + convert: WT[m*K+k] = bf16(W[k*M+m]) ----------------
__global__ __launch_bounds__(256) void k_wtrans(const float* __restrict__ W, u16* __restrict__ WT, int K, int M) {
  __shared__ float tile[32][33];
  const int k0 = blockIdx.x * 32, m0 = blockIdx.y * 32;
  const int tx = threadIdx.x & 31, ty = threadIdx.x >> 5;
#pragma unroll
  for (int j = 0; j < 4; ++j) tile[ty + j * 8][tx] = W[(size_t)(k0 + ty + j * 8) * M + m0 + tx];
  __syncthreads();
#pragma unroll
  for (int j = 0; j < 4; ++j) WT[(size_t)(m0 + ty + j * 8) * K + k0 + tx] = f2b(tile[tx][ty + j * 8]);
}

// ---------------- GEMM (m97 structure): C = act(A.Bt + bias) [+ BN(Res)] ----------------
// RESBN: residual = Res[idx]*resco[col] + resco[512+col] (on-the-fly BN of residual; Res may alias Cf).
// STATS: per-lane (sum,sumsq) -> shfl_xor(16,32) over lhi -> 1 atomic/col/wave.
template <int BM, int RELU, int HASB, int HASRES, int RESBN, int OUTF, int OUTB, int STATS, int SPLIT3>
__global__ __launch_bounds__(256) void k_gemm(const u16* __restrict__ A, const u16* __restrict__ Bt,
                                              const float* __restrict__ bias, const float* Res,
                                              const float* __restrict__ resco,
                                              float* Cf, u16* __restrict__ Cb,
                                              float* __restrict__ stats, int K, int Ncols) {
  constexpr int WR = BM / 64;
  constexpr int WC = 4 / WR;
  constexpr int MW = 4;
  constexpr int NW = 128 / (16 * WC);
  __shared__ __align__(16) u16 As[BM * 64];
  __shared__ __align__(16) u16 Bs[128 * 64];
  const int t = threadIdx.x, lane = t & 63, w = t >> 6;
  const int wr = w / WC, wc = w % WC, l16 = lane & 15, lhi = lane >> 4;
  const int row0 = blockIdx.x * BM, col0 = blockIdx.y * 128;
  const int sr = lane >> 3, sc = (lane & 7) * 8;
  const u16* Ag = A + (size_t)(row0 + sr) * K + sc;
  const u16* Bg = Bt + (size_t)(col0 + sr) * K + sc;

  f32x4 acc[MW][NW] = {};

  for (int k0 = 0; k0 < K; k0 += 64) {
    __syncthreads();
#pragma unroll
    for (int j = 0; j < BM / 32; ++j) {
      const int ch = w * (BM / 32) + j;
      gload16(Ag + (size_t)(ch * 8) * K + k0, As + ch * 512);
    }
#pragma unroll
    for (int j = 0; j < 4; ++j) {
      const int ch = w * 4 + j;
      gload16(Bg + (size_t)(ch * 8) * K + k0, Bs + ch * 512);
    }
    __syncthreads();
#pragma unroll
    for (int kk = 0; kk < 2; ++kk) {
      s16x8 af[MW], bfv[NW];
#pragma unroll
      for (int m = 0; m < MW; ++m) af[m] = *(const s16x8*)(As + (wr * 64 + m * 16 + l16) * 64 + kk * 32 + lhi * 8);
#pragma unroll
      for (int n = 0; n < NW; ++n) bfv[n] = *(const s16x8*)(Bs + (wc * (16 * NW) + n * 16 + l16) * 64 + kk * 32 + lhi * 8);
#pragma unroll
      for (int m = 0; m < MW; ++m)
#pragma unroll
        for (int n = 0; n < NW; ++n)
          acc[m][n] = __builtin_amdgcn_mfma_f32_16x16x32_bf16(af[m], bfv[n], acc[m][n], 0, 0, 0);
    }
  }

#pragma unroll
  for (int n = 0; n < NW; ++n) {
    const int col = col0 + wc * (16 * NW) + n * 16 + l16;
    float bv = 0.f;
    if constexpr (HASB) bv = bias[col];
    float ra = 0.f, rc = 0.f;
    if constexpr (RESBN) { ra = resco[col]; rc = resco[512 + col]; }
    float ssum = 0.f, ssq = 0.f;
#pragma unroll
    for (int m = 0; m < MW; ++m) {
      const int rbase = row0 + wr * 64 + m * 16 + lhi * 4;
#pragma unroll
      for (int r = 0; r < 4; ++r) {
        float v = acc[m][n][r] + bv;
        if constexpr (RELU) v = fmaxf(v, 0.f);
        const int row = rbase + r;
        const size_t idx = (size_t)row * Ncols + col;
        if constexpr (HASRES) {
          if constexpr (RESBN) v += fmaf(Res[idx], ra, rc);
          else v += Res[idx];
        }
        if constexpr (OUTF) Cf[idx] = v;
        if constexpr (OUTB) {
          if constexpr (SPLIT3) {
            const size_t ib = (size_t)(col >> 9) * QKVOFF + (size_t)row * DD + (col & 511);
            Cb[ib] = f2b(v);
          } else {
            Cb[idx] = f2b(v);
          }
        }
        if constexpr (STATS) { ssum += v; ssq += v * v; }
      }
    }
    if constexpr (STATS) {
      ssum += __shfl_xor(ssum, 16); ssq += __shfl_xor(ssq, 16);
      ssum += __shfl_xor(ssum, 32); ssq += __shfl_xor(ssq, 32);
      if (lhi == 0) {
        atomicAdd(&stats[col], ssum);
        atomicAdd(&stats[512 + col], ssq);
      }
    }
  }
}

// ---------------- attention pass 1: Z[q,k] = sum_n exp(scale * Q_[n,q,:].K_[n,k,:]) ----------------
__global__ __launch_bounds__(256) void k_attn_z(const u16* __restrict__ Q, const u16* __restrict__ Kt,
                                                float* __restrict__ Z) {
  const int t = threadIdx.x, lane = t & 63, w = t >> 6;
  const int l16 = lane & 15, lhi = lane >> 4;
  const int q0 = blockIdx.x * 64 + (w >> 1) * 32;
  const int k0 = blockIdx.y * 64 + (w & 1) * 32;
  const int n0 = blockIdx.z * 16;
  f32x4 zac[2][2] = {};
  for (int nn = 0; nn < 16; ++nn) {
    const int n = n0 + nn, h = n >> 4, b = n & 15;
    const size_t base = (size_t)b * LL * DD + (size_t)h * 32;
    s16x8 a[2], bb[2];
#pragma unroll
    for (int mi = 0; mi < 2; ++mi) a[mi] = *(const s16x8*)(Q + base + (size_t)(q0 + mi * 16 + l16) * DD + lhi * 8);
#pragma unroll
    for (int ni = 0; ni < 2; ++ni) bb[ni] = *(const s16x8*)(Kt + base + (size_t)(k0 + ni * 16 + l16) * DD + lhi * 8);
#pragma unroll
    for (int mi = 0; mi < 2; ++mi)
#pragma unroll
      for (int ni = 0; ni < 2; ++ni) {
        f32x4 z4 = {0.f, 0.f, 0.f, 0.f};
        f32x4 s = __builtin_amdgcn_mfma_f32_16x16x32_bf16(a[mi], bb[ni], z4, 0, 0, 0);
#pragma unroll
        for (int r = 0; r < 4; ++r) zac[mi][ni][r] += exp2f(s[r] * C2);
      }
  }
#pragma unroll
  for (int mi = 0; mi < 2; ++mi)
#pragma unroll
    for (int ni = 0; ni < 2; ++ni)
#pragma unroll
      for (int r = 0; r < 4; ++r)
        atomicAdd(&Z[(q0 + mi * 16 + lhi * 4 + r) * LL + k0 + ni * 16 + l16], zac[mi][ni][r]);
}

// ---------------- attention pass 2 (pv3): K/V LDS-resident; residual = BN(T_old) on the fly ----------------
__global__ __launch_bounds__(512) void k_attn_pv3(const u16* __restrict__ Q, const u16* __restrict__ K,
                                                  const u16* __restrict__ V, const float* __restrict__ IZ,
                                                  const float* __restrict__ resco, float* T,
                                                  float* __restrict__ stats) {
  __shared__ __align__(16) u16 Kl[512 * 40];  // rows padded 32->40 u16
  __shared__ __align__(16) u16 Vl[32 * 520];  // d-major rows padded 512->520 u16
  __shared__ __align__(16) u16 Pl[8][1024];   // per-wave P transpose buffer
  const int n = blockIdx.x, h = n >> 4, b = n & 15;
  const int t = threadIdx.x, lane = t & 63, w = t >> 6;
  const int l16 = lane & 15, lhi = lane >> 4;
  const size_t base = (size_t)b * LL * DD + (size_t)h * 32;

#pragma unroll
  for (int j = 0; j < 4; ++j) {
    const int c = t + j * 512;
    const int k = c >> 2, part = c & 3;
    const s16x8 v = *(const s16x8*)(K + base + (size_t)k * DD + part * 8);
    *(s16x8*)(Kl + k * 40 + part * 8) = v;
  }
#pragma unroll
  for (int j = 0; j < 4; ++j) {
    const int c = t + j * 512;
    const int k = c >> 2, dp = c & 3;
    const s16x8 v = *(const s16x8*)(V + base + (size_t)k * DD + dp * 8);
#pragma unroll
    for (int jj = 0; jj < 8; ++jj) Vl[(dp * 8 + jj) * 520 + k] = (u16)v[jj];
  }
  const int qbase = w * 64;
  s16x8 aqv[4];
#pragma unroll
  for (int qf = 0; qf < 4; ++qf)
    aqv[qf] = *(const s16x8*)(Q + base + (size_t)(qbase + qf * 16 + l16) * DD + lhi * 8);
  // residual BN coefs for this thread's two output columns
  float ra[2], rc[2];
#pragma unroll
  for (int dt = 0; dt < 2; ++dt) {
    const int col = h * 32 + dt * 16 + l16;
    ra[dt] = resco[col]; rc[dt] = resco[512 + col];
  }
  __syncthreads();

  char* P = (char*)&Pl[w][0];
  const int wxor = (l16 & 7) << 4;
  const int wbase = l16 * 128 + lhi * 8;
  float ssum[2] = {0.f, 0.f}, ssq[2] = {0.f, 0.f};

#pragma unroll
  for (int qf = 0; qf < 4; ++qf) {
    const int q16 = qbase + qf * 16;
    const float* izrow = IZ + (size_t)(q16 + l16) * LL + lhi * 4;
    f32x4 oa[2] = {};
#pragma unroll
    for (int kt = 0; kt < 8; ++kt) {
      const int kb = kt * 64;
      f32x4 s[4]; float4 iz[4];
#pragma unroll
      for (int ks = 0; ks < 4; ++ks) {
        const s16x8 af = *(const s16x8*)(Kl + (kb + ks * 16 + l16) * 40 + lhi * 8);
        f32x4 z4 = {0.f, 0.f, 0.f, 0.f};
        s[ks] = __builtin_amdgcn_mfma_f32_16x16x32_bf16(af, aqv[qf], z4, 0, 0, 0);
        iz[ks] = *(const float4*)(izrow + kb + ks * 16);
      }
#pragma unroll
      for (int ks = 0; ks < 4; ++ks) {
        const float p0 = exp2f(s[ks][0] * C2) * iz[ks].x;
        const float p1 = exp2f(s[ks][1] * C2) * iz[ks].y;
        const float p2 = exp2f(s[ks][2] * C2) * iz[ks].z;
        const float p3 = exp2f(s[ks][3] * C2) * iz[ks].w;
        unsigned int pk0, pk1;
        asm("v_cvt_pk_bf16_f32 %0, %1, %2" : "=v"(pk0) : "v"(p0), "v"(p1));
        asm("v_cvt_pk_bf16_f32 %0, %1, %2" : "=v"(pk1) : "v"(p2), "v"(p3));
        u32x2 pw; pw[0] = pk0; pw[1] = pk1;
        *(u32x2*)(P + ((wbase + ks * 32) ^ wxor)) = pw;
      }
#pragma unroll
      for (int kc = 0; kc < 2; ++kc) {
        const s16x8 pa = *(const s16x8*)(P + ((l16 * 128 + kc * 64 + lhi * 16) ^ wxor));
#pragma unroll
        for (int dt = 0; dt < 2; ++dt) {
          const s16x8 bv = *(const s16x8*)(Vl + (dt * 16 + l16) * 520 + kb + kc * 32 + lhi * 8);
          oa[dt] = __builtin_amdgcn_mfma_f32_16x16x32_bf16(pa, bv, oa[dt], 0, 0, 0);
        }
      }
    }
#pragma unroll
    for (int dt = 0; dt < 2; ++dt)
#pragma unroll
      for (int r = 0; r < 4; ++r) {
        const size_t idx = (size_t)(b * LL + q16 + lhi * 4 + r) * DD + h * 32 + dt * 16 + l16;
        const float v = oa[dt][r] + fmaf(T[idx], ra[dt], rc[dt]); // residual = BN(prev) on the fly
        T[idx] = v;
        ssum[dt] += v; ssq[dt] += v * v;
      }
  }
#pragma unroll
  for (int dt = 0; dt < 2; ++dt) {
    float su = ssum[dt], sq = ssq[dt];
    su += __shfl_xor(su, 16); sq += __shfl_xor(sq, 16);
    su += __shfl_xor(su, 32); sq += __shfl_xor(sq, 32);
    if (lhi == 0) {
      const int col = h * 32 + dt * 16 + l16;
      atomicAdd(&stats[col], su);
      atomicAdd(&stats[512 + col], sq);
    }
  }
}

// ---------------- BatchNorm finalize + apply ----------------
__global__ void k_bn_fin(float* __restrict__ S, const float* __restrict__ g,
                         const float* __restrict__ be, float* __restrict__ coef) {
  const int d = threadIdx.x;
  const float inv = 1.0f / 8192.0f;
  const float mean = S[d] * inv;
  const float var = S[512 + d] * inv - mean * mean;
  const float a = rsqrtf(var + 1e-5f) * g[d];
  coef[d] = a;
  coef[512 + d] = be[d] - mean * a;
  S[d] = 0.f; S[512 + d] = 0.f;
}

// apply -> bf16 only (f32 "encF" eliminated; consumers recompute from tF+coef)
__global__ __launch_bounds__(256) void k_bn_applyB(const float* __restrict__ X, const float* __restrict__ coef,
                                                   u16* __restrict__ Yb) {
  const int n4 = NROW * DD / 4;
  for (int i = blockIdx.x * 256 + threadIdx.x; i < n4; i += gridDim.x * 256) {
    const float4 xv = ((const float4*)X)[i];
    const int d = (i & 127) * 4;
    u16x4v o;
    o[0] = f2b(fmaf(xv.x, coef[d + 0], coef[512 + d + 0]));
    o[1] = f2b(fmaf(xv.y, coef[d + 1], coef[512 + d + 1]));
    o[2] = f2b(fmaf(xv.z, coef[d + 2], coef[512 + d + 2]));
    o[3] = f2b(fmaf(xv.w, coef[d + 3], coef[512 + d + 3]));
    ((u16x4v*)Yb)[i] = o;
  }
}

__global__ __launch_bounds__(256) void k_bn_applyF(const float* __restrict__ X, const float* __restrict__ coef,
                                                   float* __restrict__ Yf) {
  const int n4 = NROW * DD / 4;
  for (int i = blockIdx.x * 256 + threadIdx.x; i < n4; i += gridDim.x * 256) {
    const float4 xv = ((const float4*)X)[i];
    const int d = (i & 127) * 4;
    float4 o;
    o.x = fmaf(xv.x, coef[d + 0], coef[512 + d + 0]);
    o.y = fmaf(xv.y, coef[d + 1], coef[512 + d + 1]);
    o.z = fmaf(xv.z, coef[d + 2], coef[512 + d + 2]);
    o.w = fmaf(xv.w, coef[d + 3], coef[512 + d + 3]);
    ((float4*)Yf)[i] = o;
  }
}

// ---------------- host launch ----------------
extern "C" void kernel_launch(void* const* d_in, const int* in_sizes, int n_in,
                              void* d_out, int out_size, void* d_ws, size_t ws_size,
                              hipStream_t stream) {
  const float* x    = (const float*)d_in[0];
  const float* emb  = (const float*)d_in[1];
  const float* bn2g = (const float*)d_in[2];
  const float* bn2b = (const float*)d_in[3];
  const float* Wq   = (const float*)d_in[4];
  const float* bq   = (const float*)d_in[5];
  const float* Wk   = (const float*)d_in[6];
  const float* bkp  = (const float*)d_in[7];
  const float* Wv   = (const float*)d_in[8];
  const float* bvp  = (const float*)d_in[9];
  const float* bnag = (const float*)d_in[10];
  const float* bnab = (const float*)d_in[11];
  const float* W1   = (const float*)d_in[12];
  const float* b1   = (const float*)d_in[13];
  const float* W2   = (const float*)d_in[14];
  const float* b2   = (const float*)d_in[15];
  const float* bnfg = (const float*)d_in[16];
  const float* bnfb = (const float*)d_in[17];

  char* p = (char*)d_ws;
  auto alloc = [&](size_t bytes) { char* r = p; p += (bytes + 255) & ~(size_t)255; return r; };
  u16*   xb    = (u16*)alloc((size_t)NROW * DD * 2);
  u16*   encB  = (u16*)alloc((size_t)NROW * DD * 2);
  float* tF    = (float*)alloc((size_t)NROW * DD * 4);
  u16*   qkv   = (u16*)alloc((size_t)3 * NROW * DD * 2); // Q | K | V
  u16*   h1    = (u16*)alloc((size_t)NROW * FF_ * 2);
  float* Z     = (float*)alloc((size_t)LL * LL * 4);
  float* sums  = (float*)alloc(1024 * 4);
  float* coef  = (float*)alloc(1024 * 4);
  float* bqkv  = (float*)alloc(1536 * 4);
  u16*   embT  = (u16*)alloc((size_t)DD * DD * 2);
  u16*   wqkvT = (u16*)alloc((size_t)3 * DD * DD * 2);
  u16*   w1T   = (u16*)alloc((size_t)DD * FF_ * 2);
  u16*   w2T   = (u16*)alloc((size_t)FF_ * DD * 2);
  if ((size_t)(p - (char*)d_ws) > ws_size) return;

  k_zero<<<4, 256, 0, stream>>>(sums, 1024);
  k_f32_to_bf16<<<2048, 256, 0, stream>>>(x, xb, NROW * DD / 4);
  k_wtrans<<<dim3(16, 16), 256, 0, stream>>>(emb, embT, DD, DD);
  // emb conv (no bias), BM=64 grid 512 (2 blocks/CU), fused stats
  k_gemm<64, 0, 0, 0, 0, 1, 0, 1, 0><<<dim3(128, 4), 256, 0, stream>>>(
      xb, embT, nullptr, nullptr, nullptr, tF, nullptr, sums, DD, DD);
  k_bn_fin<<<1, 512, 0, stream>>>(sums, bn2g, bn2b, coef);
  k_bn_applyB<<<2048, 256, 0, stream>>>(tF, coef, encB);

  for (int i = 0; i < 3; ++i) {
    k_wtrans<<<dim3(16, 16), 256, 0, stream>>>(Wq + (size_t)i * DD * DD, wqkvT, DD, DD);
    k_wtrans<<<dim3(16, 16), 256, 0, stream>>>(Wk + (size_t)i * DD * DD, wqkvT + (size_t)512 * DD, DD, DD);
    k_wtrans<<<dim3(16, 16), 256, 0, stream>>>(Wv + (size_t)i * DD * DD, wqkvT + (size_t)1024 * DD, DD, DD);
    k_catbias<<<6, 256, 0, stream>>>(bq + i * DD, bkp + i * DD, bvp + i * DD, bqkv);
    k_gemm<128, 1, 1, 0, 0, 0, 1, 0, 1><<<dim3(64, 12), 256, 0, stream>>>(
        encB, wqkvT, bqkv, nullptr, nullptr, nullptr, qkv, nullptr, DD, 1536);
    k_zero<<<1024, 256, 0, stream>>>(Z, LL * LL);
    k_attn_z<<<dim3(8, 8, 16), 256, 0, stream>>>(qkv, qkv + QKVOFF, Z);
    k_recip<<<1024, 256, 0, stream>>>(Z, LL * LL);
    // pv3: residual = coef (prev BN) applied to tF in place
    k_attn_pv3<<<256, 512, 0, stream>>>(qkv, qkv + QKVOFF, qkv + 2 * QKVOFF, Z, coef, tF, sums);
    k_bn_fin<<<1, 512, 0, stream>>>(sums, bnag + i * DD, bnab + i * DD, coef);
    k_bn_applyB<<<2048, 256, 0, stream>>>(tF, coef, encB);
    k_wtrans<<<dim3(16, 64), 256, 0, stream>>>(W1 + (size_t)i * DD * FF_, w1T, DD, FF_);
    k_gemm<128, 1, 1, 0, 0, 0, 1, 0, 0><<<dim3(64, 16), 256, 0, stream>>>(
        encB, w1T, b1 + i * FF_, nullptr, nullptr, nullptr, h1, nullptr, DD, FF_);
    k_wtrans<<<dim3(64, 16), 256, 0, stream>>>(W2 + (size_t)i * FF_ * DD, w2T, FF_, DD);
    // FF2: BM=64 grid 512, residual = BN_a(tF) on the fly, in-place tF, fused stats
    k_gemm<64, 0, 1, 1, 1, 1, 0, 1, 0><<<dim3(128, 4), 256, 0, stream>>>(
        h1, w2T, b2 + i * DD, tF, coef, tF, nullptr, sums, FF_, DD);
    k_bn_fin<<<1, 512, 0, stream>>>(sums, bnfg + i * DD, bnfb + i * DD, coef);
    if (i == 2) k_bn_applyF<<<2048, 256, 0, stream>>>(tF, coef, (float*)d_out);
    else        k_bn_applyB<<<2048, 256, 0, stream>>>(tF, coef, encB);
  }
}

// Round 11
// 651.592 us; speedup vs baseline: 1.3773x; 1.0338x over previous
//
#include <hip/hip_runtime.h>

#define DEVI __device__ __forceinline__

typedef unsigned short u16;
typedef __attribute__((ext_vector_type(8))) short s16x8;
typedef __attribute__((ext_vector_type(4))) float f32x4;
typedef __attribute__((ext_vector_type(4))) unsigned short u16x4v;
typedef __attribute__((ext_vector_type(2))) unsigned int u32x2;

constexpr int NB   = 16;
constexpr int LL   = 512;
constexpr int DD   = 512;
constexpr int FF_  = 2048;
constexpr int NROW = NB * LL;                  // 8192
constexpr float C2 = 0.17677669529663687f * 1.4426950408889634f; // scale*log2(e)
constexpr size_t QKVOFF = (size_t)NROW * DD;   // elems per Q/K/V segment

DEVI u16 f2b(float f) {
  unsigned int u = __float_as_uint(f);
  unsigned int r = u + 0x7FFFu + ((u >> 16) & 1u); // RNE
  return (u16)(r >> 16);
}

// async global->LDS, 16B per lane; LDS dest = uniform base + lane*16
DEVI void gload16(const void* g, void* l) {
  __builtin_amdgcn_global_load_lds(
      (const __attribute__((address_space(1))) unsigned int*)(unsigned long long)g,
      (__attribute__((address_space(3))) unsigned int*)(unsigned int)(unsigned long long)l,
      16, 0, 0);
}

// ---------------- elementwise helpers ----------------
__global__ __launch_bounds__(256) void k_f32_to_bf16(const float* __restrict__ X, u16* __restrict__ Y, int n4) {
  for (int i = blockIdx.x * 256 + threadIdx.x; i < n4; i += gridDim.x * 256) {
    float4 x = ((const float4*)X)[i];
    u16x4v o; o[0] = f2b(x.x); o[1] = f2b(x.y); o[2] = f2b(x.z); o[3] = f2b(x.w);
    ((u16x4v*)Y)[i] = o;
  }
}

__global__ __launch_bounds__(256) void k_zero(float* __restrict__ p, int n) {
  int i = blockIdx.x * 256 + threadIdx.x;
  if (i < n) p[i] = 0.f;
}

__global__ __launch_bounds__(256) void k_recip(float* __restrict__ p, int n) {
  int i = blockIdx.x * 256 + threadIdx.x;
  if (i < n) p[i] = 1.0f / p[i];
}

__global__ void k_catbias(const float* __restrict__ a, const float* __restrict__ b,
                          const float* __restrict__ c, float* __restrict__ o) {
  int i = blockIdx.x * 256 + threadIdx.x; // 1536
  o[i] = (i < 512) ? a[i] : (i < 1024) ? b[i - 512] : c[i - 1024];
}

// ---------------- weight transpose + convert: WT[m*K+k] = bf16(W[k*M+m]) ----------------
__global__ __launch_bounds__(256) void k_wtrans(const float* __restrict__ W, u16* __restrict__ WT, int K, int M) {
  __shared__ float tile[32][33];
  const int k0 = blockIdx.x * 32, m0 = blockIdx.y * 32;
  const int tx = threadIdx.x & 31, ty = threadIdx.x >> 5;
#pragma unroll
  for (int j = 0; j < 4; ++j) tile[ty + j * 8][tx] = W[(size_t)(k0 + ty + j * 8) * M + m0 + tx];
  __syncthreads();
#pragma unroll
  for (int j = 0; j < 4; ++j) WT[(size_t)(m0 + ty + j * 8) * K + k0 + tx] = f2b(tile[tx][ty + j * 8]);
}

// ---------------- GEMM: C = act(A.Bt + bias) [+ BN(Res)] ----------------
// DBUF=1: 2-phase double-buffered pipeline — barrier drains prefetch(cur), then issue
// async stage(cur^1), then compute(cur); staging latency hides under MFMA phase.
// RESBN: residual = Res[idx]*resco[col] + resco[512+col]; Res may alias Cf (in-place).
// STATS: per-lane (sum,sumsq) -> shfl_xor(16,32) over lhi -> 1 atomic/col/wave.
template <int BM, int DBUF, int RELU, int HASB, int HASRES, int RESBN, int OUTF, int OUTB, int STATS, int SPLIT3>
__global__ __launch_bounds__(256) void k_gemm(const u16* __restrict__ A, const u16* __restrict__ Bt,
                                              const float* __restrict__ bias, const float* Res,
                                              const float* __restrict__ resco,
                                              float* Cf, u16* __restrict__ Cb,
                                              float* __restrict__ stats, int K, int Ncols) {
  constexpr int WR = BM / 64;
  constexpr int WC = 4 / WR;
  constexpr int MW = 4;
  constexpr int NW = 128 / (16 * WC);
  __shared__ __align__(16) u16 As[(DBUF ? 2 : 1) * BM * 64];
  __shared__ __align__(16) u16 Bs[(DBUF ? 2 : 1) * 128 * 64];
  const int t = threadIdx.x, lane = t & 63, w = t >> 6;
  const int wr = w / WC, wc = w % WC, l16 = lane & 15, lhi = lane >> 4;
  const int row0 = blockIdx.x * BM, col0 = blockIdx.y * 128;
  const int sr = lane >> 3, sc = (lane & 7) * 8;
  const u16* Ag = A + (size_t)(row0 + sr) * K + sc;
  const u16* Bg = Bt + (size_t)(col0 + sr) * K + sc;

  f32x4 acc[MW][NW] = {};

  auto stage = [&](int buf, int k0) {
    u16* Ad = As + buf * (BM * 64);
    u16* Bd = Bs + buf * (128 * 64);
#pragma unroll
    for (int j = 0; j < BM / 32; ++j) {
      const int ch = w * (BM / 32) + j;
      gload16(Ag + (size_t)(ch * 8) * K + k0, Ad + ch * 512);
    }
#pragma unroll
    for (int j = 0; j < 4; ++j) {
      const int ch = w * 4 + j;
      gload16(Bg + (size_t)(ch * 8) * K + k0, Bd + ch * 512);
    }
  };

  auto compute = [&](const u16* Ab, const u16* Bb) {
#pragma unroll
    for (int kk = 0; kk < 2; ++kk) {
      s16x8 af[MW], bfv[NW];
#pragma unroll
      for (int m = 0; m < MW; ++m) af[m] = *(const s16x8*)(Ab + (wr * 64 + m * 16 + l16) * 64 + kk * 32 + lhi * 8);
#pragma unroll
      for (int n = 0; n < NW; ++n) bfv[n] = *(const s16x8*)(Bb + (wc * (16 * NW) + n * 16 + l16) * 64 + kk * 32 + lhi * 8);
#pragma unroll
      for (int m = 0; m < MW; ++m)
#pragma unroll
        for (int n = 0; n < NW; ++n)
          acc[m][n] = __builtin_amdgcn_mfma_f32_16x16x32_bf16(af[m], bfv[n], acc[m][n], 0, 0, 0);
    }
  };

  if constexpr (DBUF) {
    stage(0, 0);
    const int NT = K >> 6;
    for (int kt = 0; kt < NT; ++kt) {
      const int cur = kt & 1;
      __syncthreads();                       // drains prefetch of buf[cur]; syncs waves
      if (kt + 1 < NT) stage(cur ^ 1, (kt + 1) << 6);  // async prefetch under compute
      compute(As + cur * (BM * 64), Bs + cur * (128 * 64));
    }
  } else {
    for (int k0 = 0; k0 < K; k0 += 64) {
      __syncthreads();
      stage(0, k0);
      __syncthreads();
      compute(As, Bs);
    }
  }

#pragma unroll
  for (int n = 0; n < NW; ++n) {
    const int col = col0 + wc * (16 * NW) + n * 16 + l16;
    float bv = 0.f;
    if constexpr (HASB) bv = bias[col];
    float ra = 0.f, rc = 0.f;
    if constexpr (RESBN) { ra = resco[col]; rc = resco[512 + col]; }
    float ssum = 0.f, ssq = 0.f;
#pragma unroll
    for (int m = 0; m < MW; ++m) {
      const int rbase = row0 + wr * 64 + m * 16 + lhi * 4;
#pragma unroll
      for (int r = 0; r < 4; ++r) {
        float v = acc[m][n][r] + bv;
        if constexpr (RELU) v = fmaxf(v, 0.f);
        const int row = rbase + r;
        const size_t idx = (size_t)row * Ncols + col;
        if constexpr (HASRES) {
          if constexpr (RESBN) v += fmaf(Res[idx], ra, rc);
          else v += Res[idx];
        }
        if constexpr (OUTF) Cf[idx] = v;
        if constexpr (OUTB) {
          if constexpr (SPLIT3) {
            const size_t ib = (size_t)(col >> 9) * QKVOFF + (size_t)row * DD + (col & 511);
            Cb[ib] = f2b(v);
          } else {
            Cb[idx] = f2b(v);
          }
        }
        if constexpr (STATS) { ssum += v; ssq += v * v; }
      }
    }
    if constexpr (STATS) {
      ssum += __shfl_xor(ssum, 16); ssq += __shfl_xor(ssq, 16);
      ssum += __shfl_xor(ssum, 32); ssq += __shfl_xor(ssq, 32);
      if (lhi == 0) {
        atomicAdd(&stats[col], ssum);
        atomicAdd(&stats[512 + col], ssq);
      }
    }
  }
}

// ---------------- attention pass 1: Z[q,k] = sum_n exp(scale * Q_[n,q,:].K_[n,k,:]) ----------------
__global__ __launch_bounds__(256) void k_attn_z(const u16* __restrict__ Q, const u16* __restrict__ Kt,
                                                float* __restrict__ Z) {
  const int t = threadIdx.x, lane = t & 63, w = t >> 6;
  const int l16 = lane & 15, lhi = lane >> 4;
  const int q0 = blockIdx.x * 64 + (w >> 1) * 32;
  const int k0 = blockIdx.y * 64 + (w & 1) * 32;
  const int n0 = blockIdx.z * 16;
  f32x4 zac[2][2] = {};
  for (int nn = 0; nn < 16; ++nn) {
    const int n = n0 + nn, h = n >> 4, b = n & 15;
    const size_t base = (size_t)b * LL * DD + (size_t)h * 32;
    s16x8 a[2], bb[2];
#pragma unroll
    for (int mi = 0; mi < 2; ++mi) a[mi] = *(const s16x8*)(Q + base + (size_t)(q0 + mi * 16 + l16) * DD + lhi * 8);
#pragma unroll
    for (int ni = 0; ni < 2; ++ni) bb[ni] = *(const s16x8*)(Kt + base + (size_t)(k0 + ni * 16 + l16) * DD + lhi * 8);
#pragma unroll
    for (int mi = 0; mi < 2; ++mi)
#pragma unroll
      for (int ni = 0; ni < 2; ++ni) {
        f32x4 z4 = {0.f, 0.f, 0.f, 0.f};
        f32x4 s = __builtin_amdgcn_mfma_f32_16x16x32_bf16(a[mi], bb[ni], z4, 0, 0, 0);
#pragma unroll
        for (int r = 0; r < 4; ++r) zac[mi][ni][r] += exp2f(s[r] * C2);
      }
  }
#pragma unroll
  for (int mi = 0; mi < 2; ++mi)
#pragma unroll
    for (int ni = 0; ni < 2; ++ni)
#pragma unroll
      for (int r = 0; r < 4; ++r)
        atomicAdd(&Z[(q0 + mi * 16 + lhi * 4 + r) * LL + k0 + ni * 16 + l16], zac[mi][ni][r]);
}

// ---------------- attention pass 2 (pv3): K/V LDS-resident; residual = BN(T_old) on the fly ----------------
__global__ __launch_bounds__(512) void k_attn_pv3(const u16* __restrict__ Q, const u16* __restrict__ K,
                                                  const u16* __restrict__ V, const float* __restrict__ IZ,
                                                  const float* __restrict__ resco, float* T,
                                                  float* __restrict__ stats) {
  __shared__ __align__(16) u16 Kl[512 * 40];  // rows padded 32->40 u16
  __shared__ __align__(16) u16 Vl[32 * 520];  // d-major rows padded 512->520 u16
  __shared__ __align__(16) u16 Pl[8][1024];   // per-wave P transpose buffer
  const int n = blockIdx.x, h = n >> 4, b = n & 15;
  const int t = threadIdx.x, lane = t & 63, w = t >> 6;
  const int l16 = lane & 15, lhi = lane >> 4;
  const size_t base = (size_t)b * LL * DD + (size_t)h * 32;

#pragma unroll
  for (int j = 0; j < 4; ++j) {
    const int c = t + j * 512;
    const int k = c >> 2, part = c & 3;
    const s16x8 v = *(const s16x8*)(K + base + (size_t)k * DD + part * 8);
    *(s16x8*)(Kl + k * 40 + part * 8) = v;
  }
#pragma unroll
  for (int j = 0; j < 4; ++j) {
    const int c = t + j * 512;
    const int k = c >> 2, dp = c & 3;
    const s16x8 v = *(const s16x8*)(V + base + (size_t)k * DD + dp * 8);
#pragma unroll
    for (int jj = 0; jj < 8; ++jj) Vl[(dp * 8 + jj) * 520 + k] = (u16)v[jj];
  }
  const int qbase = w * 64;
  s16x8 aqv[4];
#pragma unroll
  for (int qf = 0; qf < 4; ++qf)
    aqv[qf] = *(const s16x8*)(Q + base + (size_t)(qbase + qf * 16 + l16) * DD + lhi * 8);
  float ra[2], rc[2];
#pragma unroll
  for (int dt = 0; dt < 2; ++dt) {
    const int col = h * 32 + dt * 16 + l16;
    ra[dt] = resco[col]; rc[dt] = resco[512 + col];
  }
  __syncthreads();

  char* P = (char*)&Pl[w][0];
  const int wxor = (l16 & 7) << 4;
  const int wbase = l16 * 128 + lhi * 8;
  float ssum[2] = {0.f, 0.f}, ssq[2] = {0.f, 0.f};

#pragma unroll
  for (int qf = 0; qf < 4; ++qf) {
    const int q16 = qbase + qf * 16;
    const float* izrow = IZ + (size_t)(q16 + l16) * LL + lhi * 4;
    f32x4 oa[2] = {};
#pragma unroll
    for (int kt = 0; kt < 8; ++kt) {
      const int kb = kt * 64;
      f32x4 s[4]; float4 iz[4];
#pragma unroll
      for (int ks = 0; ks < 4; ++ks) {
        const s16x8 af = *(const s16x8*)(Kl + (kb + ks * 16 + l16) * 40 + lhi * 8);
        f32x4 z4 = {0.f, 0.f, 0.f, 0.f};
        s[ks] = __builtin_amdgcn_mfma_f32_16x16x32_bf16(af, aqv[qf], z4, 0, 0, 0);
        iz[ks] = *(const float4*)(izrow + kb + ks * 16);
      }
#pragma unroll
      for (int ks = 0; ks < 4; ++ks) {
        const float p0 = exp2f(s[ks][0] * C2) * iz[ks].x;
        const float p1 = exp2f(s[ks][1] * C2) * iz[ks].y;
        const float p2 = exp2f(s[ks][2] * C2) * iz[ks].z;
        const float p3 = exp2f(s[ks][3] * C2) * iz[ks].w;
        unsigned int pk0, pk1;
        asm("v_cvt_pk_bf16_f32 %0, %1, %2" : "=v"(pk0) : "v"(p0), "v"(p1));
        asm("v_cvt_pk_bf16_f32 %0, %1, %2" : "=v"(pk1) : "v"(p2), "v"(p3));
        u32x2 pw; pw[0] = pk0; pw[1] = pk1;
        *(u32x2*)(P + ((wbase + ks * 32) ^ wxor)) = pw;
      }
#pragma unroll
      for (int kc = 0; kc < 2; ++kc) {
        const s16x8 pa = *(const s16x8*)(P + ((l16 * 128 + kc * 64 + lhi * 16) ^ wxor));
#pragma unroll
        for (int dt = 0; dt < 2; ++dt) {
          const s16x8 bv = *(const s16x8*)(Vl + (dt * 16 + l16) * 520 + kb + kc * 32 + lhi * 8);
          oa[dt] = __builtin_amdgcn_mfma_f32_16x16x32_bf16(pa, bv, oa[dt], 0, 0, 0);
        }
      }
    }
#pragma unroll
    for (int dt = 0; dt < 2; ++dt)
#pragma unroll
      for (int r = 0; r < 4; ++r) {
        const size_t idx = (size_t)(b * LL + q16 + lhi * 4 + r) * DD + h * 32 + dt * 16 + l16;
        const float v = oa[dt][r] + fmaf(T[idx], ra[dt], rc[dt]);
        T[idx] = v;
        ssum[dt] += v; ssq[dt] += v * v;
      }
  }
#pragma unroll
  for (int dt = 0; dt < 2; ++dt) {
    float su = ssum[dt], sq = ssq[dt];
    su += __shfl_xor(su, 16); sq += __shfl_xor(sq, 16);
    su += __shfl_xor(su, 32); sq += __shfl_xor(sq, 32);
    if (lhi == 0) {
      const int col = h * 32 + dt * 16 + l16;
      atomicAdd(&stats[col], su);
      atomicAdd(&stats[512 + col], sq);
    }
  }
}

// ---------------- BatchNorm finalize + apply ----------------
__global__ void k_bn_fin(float* __restrict__ S, const float* __restrict__ g,
                         const float* __restrict__ be, float* __restrict__ coef) {
  const int d = threadIdx.x;
  const float inv = 1.0f / 8192.0f;
  const float mean = S[d] * inv;
  const float var = S[512 + d] * inv - mean * mean;
  const float a = rsqrtf(var + 1e-5f) * g[d];
  coef[d] = a;
  coef[512 + d] = be[d] - mean * a;
  S[d] = 0.f; S[512 + d] = 0.f;
}

__global__ __launch_bounds__(256) void k_bn_applyB(const float* __restrict__ X, const float* __restrict__ coef,
                                                   u16* __restrict__ Yb) {
  const int n4 = NROW * DD / 4;
  for (int i = blockIdx.x * 256 + threadIdx.x; i < n4; i += gridDim.x * 256) {
    const float4 xv = ((const float4*)X)[i];
    const int d = (i & 127) * 4;
    u16x4v o;
    o[0] = f2b(fmaf(xv.x, coef[d + 0], coef[512 + d + 0]));
    o[1] = f2b(fmaf(xv.y, coef[d + 1], coef[512 + d + 1]));
    o[2] = f2b(fmaf(xv.z, coef[d + 2], coef[512 + d + 2]));
    o[3] = f2b(fmaf(xv.w, coef[d + 3], coef[512 + d + 3]));
    ((u16x4v*)Yb)[i] = o;
  }
}

__global__ __launch_bounds__(256) void k_bn_applyF(const float* __restrict__ X, const float* __restrict__ coef,
                                                   float* __restrict__ Yf) {
  const int n4 = NROW * DD / 4;
  for (int i = blockIdx.x * 256 + threadIdx.x; i < n4; i += gridDim.x * 256) {
    const float4 xv = ((const float4*)X)[i];
    const int d = (i & 127) * 4;
    float4 o;
    o.x = fmaf(xv.x, coef[d + 0], coef[512 + d + 0]);
    o.y = fmaf(xv.y, coef[d + 1], coef[512 + d + 1]);
    o.z = fmaf(xv.z, coef[d + 2], coef[512 + d + 2]);
    o.w = fmaf(xv.w, coef[d + 3], coef[512 + d + 3]);
    ((float4*)Yf)[i] = o;
  }
}

// ---------------- host launch ----------------
extern "C" void kernel_launch(void* const* d_in, const int* in_sizes, int n_in,
                              void* d_out, int out_size, void* d_ws, size_t ws_size,
                              hipStream_t stream) {
  const float* x    = (const float*)d_in[0];
  const float* emb  = (const float*)d_in[1];
  const float* bn2g = (const float*)d_in[2];
  const float* bn2b = (const float*)d_in[3];
  const float* Wq   = (const float*)d_in[4];
  const float* bq   = (const float*)d_in[5];
  const float* Wk   = (const float*)d_in[6];
  const float* bkp  = (const float*)d_in[7];
  const float* Wv   = (const float*)d_in[8];
  const float* bvp  = (const float*)d_in[9];
  const float* bnag = (const float*)d_in[10];
  const float* bnab = (const float*)d_in[11];
  const float* W1   = (const float*)d_in[12];
  const float* b1   = (const float*)d_in[13];
  const float* W2   = (const float*)d_in[14];
  const float* b2   = (const float*)d_in[15];
  const float* bnfg = (const float*)d_in[16];
  const float* bnfb = (const float*)d_in[17];

  char* p = (char*)d_ws;
  auto alloc = [&](size_t bytes) { char* r = p; p += (bytes + 255) & ~(size_t)255; return r; };
  u16*   xb    = (u16*)alloc((size_t)NROW * DD * 2);
  u16*   encB  = (u16*)alloc((size_t)NROW * DD * 2);
  float* tF    = (float*)alloc((size_t)NROW * DD * 4);
  u16*   qkv   = (u16*)alloc((size_t)3 * NROW * DD * 2); // Q | K | V
  u16*   h1    = (u16*)alloc((size_t)NROW * FF_ * 2);
  float* Z     = (float*)alloc((size_t)LL * LL * 4);
  float* sums  = (float*)alloc(1024 * 4);
  float* coef  = (float*)alloc(1024 * 4);
  float* bqkv  = (float*)alloc(1536 * 4);
  u16*   embT  = (u16*)alloc((size_t)DD * DD * 2);
  u16*   wqkvT = (u16*)alloc((size_t)3 * DD * DD * 2);
  u16*   w1T   = (u16*)alloc((size_t)DD * FF_ * 2);
  u16*   w2T   = (u16*)alloc((size_t)FF_ * DD * 2);
  if ((size_t)(p - (char*)d_ws) > ws_size) return;

  k_zero<<<4, 256, 0, stream>>>(sums, 1024);
  k_f32_to_bf16<<<2048, 256, 0, stream>>>(x, xb, NROW * DD / 4);
  k_wtrans<<<dim3(16, 16), 256, 0, stream>>>(emb, embT, DD, DD);
  // emb conv (no bias), BM=64, double-buffered, fused stats
  k_gemm<64, 1, 0, 0, 0, 0, 1, 0, 1, 0><<<dim3(128, 4), 256, 0, stream>>>(
      xb, embT, nullptr, nullptr, nullptr, tF, nullptr, sums, DD, DD);
  k_bn_fin<<<1, 512, 0, stream>>>(sums, bn2g, bn2b, coef);
  k_bn_applyB<<<2048, 256, 0, stream>>>(tF, coef, encB);

  for (int i = 0; i < 3; ++i) {
    k_wtrans<<<dim3(16, 16), 256, 0, stream>>>(Wq + (size_t)i * DD * DD, wqkvT, DD, DD);
    k_wtrans<<<dim3(16, 16), 256, 0, stream>>>(Wk + (size_t)i * DD * DD, wqkvT + (size_t)512 * DD, DD, DD);
    k_wtrans<<<dim3(16, 16), 256, 0, stream>>>(Wv + (size_t)i * DD * DD, wqkvT + (size_t)1024 * DD, DD, DD);
    k_catbias<<<6, 256, 0, stream>>>(bq + i * DD, bkp + i * DD, bvp + i * DD, bqkv);
    k_gemm<128, 0, 1, 1, 0, 0, 0, 1, 0, 1><<<dim3(64, 12), 256, 0, stream>>>(
        encB, wqkvT, bqkv, nullptr, nullptr, nullptr, qkv, nullptr, DD, 1536);
    k_zero<<<1024, 256, 0, stream>>>(Z, LL * LL);
    k_attn_z<<<dim3(8, 8, 16), 256, 0, stream>>>(qkv, qkv + QKVOFF, Z);
    k_recip<<<1024, 256, 0, stream>>>(Z, LL * LL);
    k_attn_pv3<<<256, 512, 0, stream>>>(qkv, qkv + QKVOFF, qkv + 2 * QKVOFF, Z, coef, tF, sums);
    k_bn_fin<<<1, 512, 0, stream>>>(sums, bnag + i * DD, bnab + i * DD, coef);
    k_bn_applyB<<<2048, 256, 0, stream>>>(tF, coef, encB);
    k_wtrans<<<dim3(16, 64), 256, 0, stream>>>(W1 + (size_t)i * DD * FF_, w1T, DD, FF_);
    k_gemm<128, 0, 1, 1, 0, 0, 0, 1, 0, 0><<<dim3(64, 16), 256, 0, stream>>>(
        encB, w1T, b1 + i * FF_, nullptr, nullptr, nullptr, h1, nullptr, DD, FF_);
    k_wtrans<<<dim3(64, 16), 256, 0, stream>>>(W2 + (size_t)i * FF_ * DD, w2T, FF_, DD);
    // FF2: BM=64, double-buffered, residual = BN_a(tF) on the fly, in-place tF, fused stats
    k_gemm<64, 1, 0, 1, 1, 1, 1, 0, 1, 0><<<dim3(128, 4), 256, 0, stream>>>(
        h1, w2T, b2 + i * DD, tF, coef, tF, nullptr, sums, FF_, DD);
    k_bn_fin<<<1, 512, 0, stream>>>(sums, bnfg + i * DD, bnfb + i * DD, coef);
    if (i == 2) k_bn_applyF<<<2048, 256, 0, stream>>>(tF, coef, (float*)d_out);
    else        k_bn_applyB<<<2048, 256, 0, stream>>>(tF, coef, encB);
  }
}